// Round 5
// baseline (184.991 us; speedup 1.0000x reference)
//
#include <hip/hip_runtime.h>
#include <math.h>

typedef unsigned int uint;
typedef unsigned long long u64;

#define NT 256
#define KTOP 200
#define CAP 256      // final candidate cap == NT (rank-sort)
#define CAPC 3072    // LDS candidate-list cap
#define NCLS 21
#define C1 20
#define MROWS 208
#define NSPLIT 32    // prep blocks per batch image

__device__ __forceinline__ uint f32_key(float f) {
  uint u = __float_as_uint(f);
  return (u & 0x80000000u) ? ~u : (u | 0x80000000u);
}

__device__ __forceinline__ u64 flip64(double d) {
  u64 u = (u64)__double_as_longlong(d);
  return (u & 0x8000000000000000ULL) ? ~u : (u | 0x8000000000000000ULL);
}

__device__ __forceinline__ double unflip64(u64 k) {
  u64 u = (k & 0x8000000000000000ULL) ? (k ^ 0x8000000000000000ULL) : ~k;
  return __longlong_as_double((long long)u);
}

// ---- K1: decode boxes + f64 LSE + keys + fused per-task 8-bit MSB histogram ----
__global__ __launch_bounds__(NT) void prep_kernel(
    const float* __restrict__ bboxes,   // [B,4,N]
    const float* __restrict__ scores,   // [B,21,N]
    const float* __restrict__ dboxes,   // [N,4]
    const float* __restrict__ conf_th,  // [20]
    const float* __restrict__ scale_xy_p,
    const float* __restrict__ scale_wh_p,
    float4* __restrict__ boxes_out,     // [B*N]
    double* __restrict__ lse_out,       // [B*N]
    uint*  __restrict__ keys_out,       // [B,20,N]
    uint*  __restrict__ ghist,          // [B*20,256]
    int B, int N, int perblk)
{
  __shared__ double s_logth[C1];
  __shared__ uint lhist[C1 * 256];
  int tid = threadIdx.x;
  if (tid < C1) s_logth[tid] = log((double)conf_th[tid]);
  for (int i = tid; i < C1 * 256; i += NT) lhist[i] = 0;
  __syncthreads();

  int b = blockIdx.x / NSPLIT, j = blockIdx.x - (blockIdx.x / NSPLIT) * NSPLIT;
  int s0 = j * perblk, e0 = min(N, s0 + perblk);
  float sxy = *scale_xy_p, swh = *scale_wh_p;

  for (int n = s0 + tid; n < e0; n += NT) {
    int gid = b * N + n;
    const float* bb = bboxes + (size_t)b * 4 * N + n;
    float bx = bb[0];
    float by = bb[(size_t)N];
    float bw = bb[2 * (size_t)N];
    float bh = bb[3 * (size_t)N];
    float4 d = reinterpret_cast<const float4*>(dboxes)[n];
    float x = sxy * bx * d.z + d.x;
    float y = sxy * by * d.w + d.y;
    float w = expf(swh * bw) * d.z;
    float h = expf(swh * bh) * d.w;
    boxes_out[gid] = make_float4(x - 0.5f * w, y - 0.5f * h, x + 0.5f * w, y + 0.5f * h);

    const float* sc = scores + (size_t)b * NCLS * N + n;
    float v[NCLS];
    float mx = -INFINITY;
#pragma unroll
    for (int c = 0; c < NCLS; ++c) { v[c] = sc[(size_t)c * N]; mx = fmaxf(mx, v[c]); }
    double sum = 0.0;
#pragma unroll
    for (int c = 0; c < NCLS; ++c) sum += exp((double)(v[c] - mx));
    double lse = (double)mx + log(sum);
    lse_out[gid] = lse;

#pragma unroll
    for (int c = 0; c < C1; ++c) {
      double s = (double)v[c + 1] - lse;
      uint key = 0;
      if (s > s_logth[c]) key = f32_key((float)s);
      keys_out[((size_t)b * C1 + c) * N + n] = key;
      if (key) atomicAdd(&lhist[c * 256 + (key >> 24)], 1u);
    }
  }
  __syncthreads();
  for (int i = tid; i < C1 * 256; i += NT) {
    uint v = lhist[i];
    if (v) atomicAdd(&ghist[((size_t)b * C1 + (i >> 8)) * 256 + (i & 255)], v);
  }
}

// ---- K2: per-task walk of the 256-bin hist (1 wave per task) -------------------
__global__ __launch_bounds__(64) void walk_kernel(
    const uint* __restrict__ ghist, uint4* __restrict__ L0cnt)
{
  int task = blockIdx.x;
  int lane = threadIdx.x;
  uint4 h = reinterpret_cast<const uint4*>(ghist + (size_t)task * 256)[lane];
  uint s = h.x + h.y + h.z + h.w;
  uint suf = s;
#pragma unroll
  for (int off = 1; off < 64; off <<= 1) {
    uint o = (uint)__shfl_down((int)suf, off);
    if (lane + off < 64) suf += o;
  }
  uint total = (uint)__shfl((int)suf, 0);
  uint sn = (uint)__shfl_down((int)suf, 1);
  if (lane == 63) sn = 0;
  // per-lane: counts from top within this lane's 4 bins
  uint c3 = h.w + sn, c2 = c3 + h.z, c1 = c2 + h.y, c0 = c1 + h.x;
  uint binoff, cnt, abv;
  if (c3 >= KTOP)      { binoff = 3; cnt = c3; abv = c3 - h.w; }
  else if (c2 >= KTOP) { binoff = 2; cnt = c2; abv = c2 - h.z; }
  else if (c1 >= KTOP) { binoff = 1; cnt = c1; abv = c1 - h.y; }
  else                 { binoff = 0; cnt = c0; abv = c0 - h.x; }
  uint L0v, cnt0v, abovev;
  if (total < KTOP) {
    L0v = 1u; cnt0v = total; abovev = 0u;
  } else {
    u64 m = __ballot(suf >= KTOP);
    int l = 63 - __clzll(m);
    uint bo = (uint)__shfl((int)binoff, l);
    cnt0v = (uint)__shfl((int)cnt, l);
    abovev = (uint)__shfl((int)abv, l);
    L0v = ((uint)(4 * l) + bo) << 24;
  }
  if (lane == 0) L0cnt[task] = make_uint4(L0v, cnt0v, abovev, total);
}

// ---- K3: single-pass collect + LDS narrowing + rank-sort + NMS + output --------
__global__ __launch_bounds__(NT) void select_nms_kernel(
    const uint*  __restrict__ keys,     // [B*20,N]
    const uint4* __restrict__ L0cnt,
    const float* __restrict__ scores,
    const double* __restrict__ lse,
    const float4* __restrict__ boxesws,
    const float* __restrict__ nms_th_p,
    float* __restrict__ out, int B, int N)
{
  int task = blockIdx.x;
  int b = task / C1, c = task - b * C1;
  int tid = threadIdx.x, lane = tid & 63;
  const uint* krow = keys + (size_t)task * N;
  const uint4* krow4 = reinterpret_cast<const uint4*>(krow);
  int nv = N >> 2;

  __shared__ u64 cand[CAPC];             // 24 KB
  __shared__ uint histB[256];
  __shared__ int si[CAP];
  __shared__ u64 skey[CAP];
  __shared__ u64 skid[CAP];
  __shared__ float bl[KTOP], bt[KTOP], br_[KTOP], bb_[KTOP];
  __shared__ double sarea[KTOP];
  __shared__ u64 smask[MROWS][4];
  __shared__ u64 saliveW[4];
  __shared__ uint sCnt, sCnt2, sCur, sAbove, sPref;

  uint4 w0 = L0cnt[task];
  uint L0 = w0.x, cnt0 = w0.y, above0 = w0.z;

  // ---------- rare: refine threshold over the row until count <= CAPC
  uint pref = L0 >> 24, above = above0, rank = KTOP - above0, cur = cnt0;
  int shift = 24;
  uint L = L0;
  while (cur > CAPC && shift > 0) {
    shift -= 8;
    if (tid < 256) histB[tid] = 0;
    __syncthreads();
    for (int i = tid; i < nv; i += NT) {
      uint4 kv = krow4[i];
      if ((kv.x >> (shift + 8)) == pref) atomicAdd(&histB[(kv.x >> shift) & 255u], 1u);
      if ((kv.y >> (shift + 8)) == pref) atomicAdd(&histB[(kv.y >> shift) & 255u], 1u);
      if ((kv.z >> (shift + 8)) == pref) atomicAdd(&histB[(kv.z >> shift) & 255u], 1u);
      if ((kv.w >> (shift + 8)) == pref) atomicAdd(&histB[(kv.w >> shift) & 255u], 1u);
    }
    for (int n0 = nv << 2; n0 < N; n0 += NT) {
      int n = n0 + tid;
      if (n < N) {
        uint k = krow[n];
        if ((k >> (shift + 8)) == pref) atomicAdd(&histB[(k >> shift) & 255u], 1u);
      }
    }
    __syncthreads();
    if (tid == 0) {
      uint cum = 0; int bin = 255;
      for (int jj = 255; jj >= 0; --jj) { cum += histB[jj]; if (cum >= rank) { bin = jj; break; } }
      sCur = above + cum;
      sAbove = above + cum - histB[bin];
      sPref = (pref << 8) | (uint)bin;
    }
    __syncthreads();
    cur = sCur; above = sAbove; pref = sPref; rank = KTOP - above;
    L = pref << shift;
    __syncthreads();
  }

  // ---------- collect pass: ballot-compaction, zero per-element atomics
  if (tid == 0) sCnt = 0;
  __syncthreads();
  for (int i = tid; i < nv; i += NT) {
    uint4 kv = krow4[i];
    int base = i << 2;
#pragma unroll
    for (int comp = 0; comp < 4; ++comp) {
      uint k = (comp == 0) ? kv.x : (comp == 1) ? kv.y : (comp == 2) ? kv.z : kv.w;
      bool f = (k >= L);
      u64 m = __ballot(f);
      if (m) {
        uint nb = (uint)__popcll(m);
        uint wb = 0;
        if (lane == 0) wb = atomicAdd(&sCnt, nb);
        wb = (uint)__shfl((int)wb, 0);
        if (f) {
          uint pos = wb + (uint)__popcll(m & ((1ULL << lane) - 1ULL));
          if (pos < CAPC) cand[pos] = ((u64)k << 32) | (uint)(base + comp);
        }
      }
    }
  }
  for (int n0 = nv << 2; n0 < N; n0 += NT) {
    int n = n0 + tid;
    uint k = (n < N) ? krow[n] : 0u;
    bool f = (k >= L) && (n < N);
    u64 m = __ballot(f);
    if (m) {
      uint nb = (uint)__popcll(m);
      uint wb = 0;
      if (lane == 0) wb = atomicAdd(&sCnt, nb);
      wb = (uint)__shfl((int)wb, 0);
      if (f) {
        uint pos = wb + (uint)__popcll(m & ((1ULL << lane) - 1ULL));
        if (pos < CAPC) cand[pos] = ((u64)k << 32) | (uint)n;
      }
    }
  }
  __syncthreads();
  uint cnt = min(sCnt, (uint)CAPC);

  // ---------- narrow candidate list to <= CAP (LDS-resident radix walk)
  uint cntF;
  if (cnt <= CAP) {
    for (int p = tid; p < (int)cnt; p += NT) si[p] = (int)(uint)cand[p];
    __syncthreads();
    cntF = cnt;
  } else {
    uint pref2 = 0, above2 = 0, rank2 = KTOP, cur2 = cnt;
    int sh = 32;
    while (cur2 > CAP && sh > 0) {
      sh -= 8;
      if (tid < 256) histB[tid] = 0;
      __syncthreads();
      for (int p = tid; p < (int)cnt; p += NT) {
        uint k = (uint)(cand[p] >> 32);
        if (sh == 24 || (k >> (sh + 8)) == pref2) atomicAdd(&histB[(k >> sh) & 255u], 1u);
      }
      __syncthreads();
      if (tid == 0) {
        uint cum = 0; int bin = 255;
        for (int jj = 255; jj >= 0; --jj) { cum += histB[jj]; if (cum >= rank2) { bin = jj; break; } }
        sCur = above2 + cum;
        sAbove = above2 + cum - histB[bin];
        sPref = (sh == 24) ? (uint)bin : ((pref2 << 8) | (uint)bin);
      }
      __syncthreads();
      cur2 = sCur; above2 = sAbove; pref2 = sPref; rank2 = KTOP - above2;
      __syncthreads();
    }
    uint T = pref2 << sh;
    if (tid == 0) sCnt2 = 0;
    __syncthreads();
    for (int p = tid; p < (int)cnt; p += NT) {
      u64 e = cand[p];
      uint k = (uint)(e >> 32);
      if (k >= T) { uint q = atomicAdd(&sCnt2, 1u); if (q < CAP) si[q] = (int)(uint)e; }
    }
    __syncthreads();
    cntF = min(sCnt2, (uint)CAP);
  }

  int valid_cnt = (int)min(cntF, (uint)KTOP);

  // ---------- gather exact f64 scores; pad; rank-sort (one barrier)
  {
    int p = tid;
    if (p < (int)cntF) {
      int n = si[p];
      double s = (double)scores[((size_t)b * NCLS + (c + 1)) * N + n] - lse[(size_t)b * N + n];
      skey[p] = flip64(s);
    } else {
      skey[p] = 0ULL;
      si[p] = 0x40000000 + p;
    }
  }
  __syncthreads();
  {
    u64 kp = skey[tid];
    int ip = si[tid];
    int r = 0;
#pragma unroll 4
    for (int jj = 0; jj < CAP; ++jj) {
      u64 kj = skey[jj];
      int ij = si[jj];
      r += ((kj > kp) || (kj == kp && ij < ip)) ? 1 : 0;
    }
    skid[r] = kp;
    if (tid < (int)cntF && r < KTOP) {
      float4 bx = boxesws[(size_t)b * N + ip];
      bl[r] = bx.x; bt[r] = bx.y; br_[r] = bx.z; bb_[r] = bx.w;
      double w = fmax((double)bx.z - (double)bx.x, 0.0);
      double h = fmax((double)bx.w - (double)bx.y, 0.0);
      sarea[r] = w * h;
    }
  }
  __syncthreads();

  double nth = (double)(*nms_th_p);

  // ---------- 208x4-word suppression bitmask
  for (int u = tid; u < MROWS * 4; u += NT) {
    int i = u >> 2, w = u & 3;
    u64 m = 0;
    if (i < valid_cnt) {
      int j0 = max(i + 1, w * 64);
      int j1 = min(valid_cnt, w * 64 + 64);
      double li = (double)bl[i], ti = (double)bt[i];
      double ri = (double)br_[i], bi = (double)bb_[i];
      double ai = sarea[i];
      for (int jj = j0; jj < j1; ++jj) {
        double xx1 = fmax(li, (double)bl[jj]);
        double yy1 = fmax(ti, (double)bt[jj]);
        double xx2 = fmin(ri, (double)br_[jj]);
        double yy2 = fmin(bi, (double)bb_[jj]);
        double ww = fmax(xx2 - xx1, 0.0), hh = fmax(yy2 - yy1, 0.0);
        double inter = ww * hh;
        double iou = inter / (ai + sarea[jj] - inter + 1e-9);
        if (iou >= nth) m |= 1ULL << (jj - w * 64);
      }
    }
    smask[i][w] = m;
  }
  __syncthreads();

  // ---------- greedy resolve: wave 0, masks in registers, pure VALU chain
  if (tid < 64) {
    int row = lane >> 2, col = lane & 3;
#define LOADM(cc) u64 M##cc = smask[(cc) * 16 + row][col];
    LOADM(0) LOADM(1) LOADM(2) LOADM(3) LOADM(4) LOADM(5) LOADM(6)
    LOADM(7) LOADM(8) LOADM(9) LOADM(10) LOADM(11) LOADM(12)
#undef LOADM
    int vc = valid_cnt;
    u64 aw0, aw1, aw2, aw3;
    {
      int n0 = vc, n1 = vc - 64, n2 = vc - 128, n3 = vc - 192;
      aw0 = (n0 >= 64) ? ~0ULL : ((n0 > 0) ? ((1ULL << n0) - 1) : 0ULL);
      aw1 = (n1 >= 64) ? ~0ULL : ((n1 > 0) ? ((1ULL << n1) - 1) : 0ULL);
      aw2 = (n2 >= 64) ? ~0ULL : ((n2 > 0) ? ((1ULL << n2) - 1) : 0ULL);
      aw3 = (n3 >= 64) ? ~0ULL : ((n3 > 0) ? ((1ULL << n3) - 1) : 0ULL);
    }
    u64 kp0 = 0, kp1 = 0, kp2 = 0, kp3 = 0;
#define GREEDY_CHUNK(cc, AW, KP) { \
    uint fld = (uint)((AW >> (((cc) & 3) * 16)) & 0xFFFFULL); \
    while (fld) { \
      int bi = __ffs(fld) - 1; \
      int slot = bi << 2; \
      u64 mw0 = __shfl(M##cc, slot); \
      u64 mw1 = __shfl(M##cc, slot + 1); \
      u64 mw2 = __shfl(M##cc, slot + 2); \
      u64 mw3 = __shfl(M##cc, slot + 3); \
      aw0 &= ~mw0; aw1 &= ~mw1; aw2 &= ~mw2; aw3 &= ~mw3; \
      KP |= 1ULL << (((cc) & 3) * 16 + bi); \
      fld = ((uint)((AW >> (((cc) & 3) * 16)) & 0xFFFFULL)) & (uint)(0xFFFFu << (bi + 1)); \
    } }
    GREEDY_CHUNK(0, aw0, kp0) GREEDY_CHUNK(1, aw0, kp0)
    GREEDY_CHUNK(2, aw0, kp0) GREEDY_CHUNK(3, aw0, kp0)
    GREEDY_CHUNK(4, aw1, kp1) GREEDY_CHUNK(5, aw1, kp1)
    GREEDY_CHUNK(6, aw1, kp1) GREEDY_CHUNK(7, aw1, kp1)
    GREEDY_CHUNK(8, aw2, kp2) GREEDY_CHUNK(9, aw2, kp2)
    GREEDY_CHUNK(10, aw2, kp2) GREEDY_CHUNK(11, aw2, kp2)
    GREEDY_CHUNK(12, aw3, kp3)
#undef GREEDY_CHUNK
    if (lane == 0) { saliveW[0] = kp0; saliveW[1] = kp1; saliveW[2] = kp2; saliveW[3] = kp3; }
  }
  __syncthreads();

  // ---------- outputs: boxes | labels | scores | keep
  size_t M = (size_t)C1 * KTOP;
  float* out_boxes  = out;
  float* out_labels = out + (size_t)B * M * 4;
  float* out_scores = out_labels + (size_t)B * M;
  float* out_keep   = out_scores + (size_t)B * M;
  if (tid < KTOP) {
    size_t slot = ((size_t)b * C1 + c) * KTOP + tid;
    bool kept = (tid < valid_cnt) && ((saliveW[tid >> 6] >> (tid & 63)) & 1ULL);
    float4 bx = kept ? make_float4(bl[tid], bt[tid], br_[tid], bb_[tid])
                     : make_float4(0.f, 0.f, 0.f, 0.f);
    reinterpret_cast<float4*>(out_boxes)[slot] = bx;
    out_labels[slot] = kept ? (float)(c + 1) : 0.0f;
    out_scores[slot] = kept ? (float)exp(unflip64(skid[tid])) : 0.0f;
    out_keep[slot]   = kept ? 1.0f : 0.0f;
  }
}

extern "C" void kernel_launch(void* const* d_in, const int* in_sizes, int n_in,
                              void* d_out, int out_size, void* d_ws, size_t ws_size,
                              hipStream_t stream) {
  const float* bboxes   = (const float*)d_in[0];   // [B,4,N]
  const float* scores   = (const float*)d_in[1];   // [B,21,N]
  const float* dboxes   = (const float*)d_in[2];   // [1,N,4]
  const float* conf_th  = (const float*)d_in[3];   // [20]
  const float* nms_th   = (const float*)d_in[4];   // scalar
  const float* scale_xy = (const float*)d_in[6];   // scalar
  const float* scale_wh = (const float*)d_in[7];   // scalar

  int N = in_sizes[2] / 4;
  int B = in_sizes[0] / (4 * N);

  // ws layout: lse f64 | boxes float4 | keys u32 | ghist u32 | L0cnt uint4
  char* ws = (char*)d_ws;
  size_t off = 0;
  double* lse     = (double*)(ws + off); off += (size_t)B * N * 8;
  float4* boxesws = (float4*)(ws + off); off += (size_t)B * N * 16;
  uint*   keys    = (uint*)  (ws + off); off += (size_t)B * C1 * N * 4;
  uint*   ghist   = (uint*)  (ws + off); off += (size_t)B * C1 * 256 * 4;
  uint4*  L0cnt   = (uint4*) (ws + off);

  hipMemsetAsync(ghist, 0, (size_t)B * C1 * 256 * 4, stream);

  int perblk = (N + NSPLIT - 1) / NSPLIT;
  prep_kernel<<<B * NSPLIT, NT, 0, stream>>>(
      bboxes, scores, dboxes, conf_th, scale_xy, scale_wh,
      boxesws, lse, keys, ghist, B, N, perblk);

  walk_kernel<<<B * C1, 64, 0, stream>>>(ghist, L0cnt);

  select_nms_kernel<<<B * C1, NT, 0, stream>>>(
      keys, L0cnt, scores, lse, boxesws, nms_th, (float*)d_out, B, N);
}

// Round 6
// 159.583 us; speedup vs baseline: 1.1592x; 1.1592x over previous
//
#include <hip/hip_runtime.h>
#include <math.h>

typedef unsigned int uint;
typedef unsigned long long u64;

#define NT 256
#define KTOP 200
#define CAP 256      // final candidate cap == NT (rank-sort)
#define CAPC 3072    // LDS candidate-list cap (final kernel)
#define SEGS 4       // collect segments per task
#define SEGCAP 768   // per-segment candidate cap in global
#define NCLS 21
#define C1 20
#define MROWS 208
#define NSPLIT 32    // prep blocks per batch image

__device__ __forceinline__ u64 flip64(double d) {
  u64 u = (u64)__double_as_longlong(d);
  return (u & 0x8000000000000000ULL) ? ~u : (u | 0x8000000000000000ULL);
}

__device__ __forceinline__ double unflip64(u64 k) {
  u64 u = (k & 0x8000000000000000ULL) ? (k ^ 0x8000000000000000ULL) : ~k;
  return __longlong_as_double((long long)u);
}

// monotone fixed-point key for s = log prob (s <= 0); 26-bit, 0 = invalid
__device__ __forceinline__ uint q_key(float sf) {
  float qf = (sf + 16.0f) * 4194304.0f;          // exact *2^22
  qf = fmaxf(fminf(qf, 67108863.0f), 1.0f);
  return (uint)qf;
}

// ---- K1: decode boxes + f64 LSE + fixed-point keys + fused 256-bin hist ----
__global__ __launch_bounds__(NT) void prep_kernel(
    const float* __restrict__ bboxes,   // [B,4,N]
    const float* __restrict__ scores,   // [B,21,N]
    const float* __restrict__ dboxes,   // [N,4]
    const float* __restrict__ conf_th,  // [20]
    const float* __restrict__ scale_xy_p,
    const float* __restrict__ scale_wh_p,
    float4* __restrict__ boxes_out,     // [B*N]
    double* __restrict__ lse_out,       // [B*N]
    uint*  __restrict__ keys_out,       // [B,20,N]
    uint*  __restrict__ ghist,          // [B*20,256]
    int B, int N, int perblk)
{
  __shared__ double s_logth[C1];
  __shared__ uint lhist[C1 * 256];
  int tid = threadIdx.x;
  if (tid < C1) s_logth[tid] = log((double)conf_th[tid]);
  for (int i = tid; i < C1 * 256; i += NT) lhist[i] = 0;
  __syncthreads();

  int b = blockIdx.x / NSPLIT, j = blockIdx.x - (blockIdx.x / NSPLIT) * NSPLIT;
  int s0 = j * perblk, e0 = min(N, s0 + perblk);
  float sxy = *scale_xy_p, swh = *scale_wh_p;

  for (int n = s0 + tid; n < e0; n += NT) {
    int gid = b * N + n;
    const float* bb = bboxes + (size_t)b * 4 * N + n;
    float bx = bb[0];
    float by = bb[(size_t)N];
    float bw = bb[2 * (size_t)N];
    float bh = bb[3 * (size_t)N];
    float4 d = reinterpret_cast<const float4*>(dboxes)[n];
    float x = sxy * bx * d.z + d.x;
    float y = sxy * by * d.w + d.y;
    float w = expf(swh * bw) * d.z;
    float h = expf(swh * bh) * d.w;
    boxes_out[gid] = make_float4(x - 0.5f * w, y - 0.5f * h, x + 0.5f * w, y + 0.5f * h);

    const float* sc = scores + (size_t)b * NCLS * N + n;
    float v[NCLS];
    float mx = -INFINITY;
#pragma unroll
    for (int c = 0; c < NCLS; ++c) { v[c] = sc[(size_t)c * N]; mx = fmaxf(mx, v[c]); }
    double sum = 0.0;
#pragma unroll
    for (int c = 0; c < NCLS; ++c) sum += exp((double)(v[c] - mx));
    double lse = (double)mx + log(sum);
    lse_out[gid] = lse;

#pragma unroll
    for (int c = 0; c < C1; ++c) {
      double s = (double)v[c + 1] - lse;
      uint key = 0;
      if (s > s_logth[c]) key = q_key((float)s);
      keys_out[((size_t)b * C1 + c) * N + n] = key;
      if (key) atomicAdd(&lhist[c * 256 + (key >> 18)], 1u);
    }
  }
  __syncthreads();
  for (int i = tid; i < C1 * 256; i += NT) {
    uint v = lhist[i];
    if (v) atomicAdd(&ghist[((size_t)b * C1 + (i >> 8)) * 256 + (i & 255)], v);
  }
}

// ---- K2: per-task walk of the 256-bin hist (1 wave per task) ----------------
__global__ __launch_bounds__(64) void walk_kernel(
    const uint* __restrict__ ghist, uint4* __restrict__ L0cnt)
{
  int task = blockIdx.x;
  int lane = threadIdx.x;
  uint4 h = reinterpret_cast<const uint4*>(ghist + (size_t)task * 256)[lane];
  uint s = h.x + h.y + h.z + h.w;
  uint suf = s;
#pragma unroll
  for (int off = 1; off < 64; off <<= 1) {
    uint o = (uint)__shfl_down((int)suf, off);
    if (lane + off < 64) suf += o;
  }
  uint total = (uint)__shfl((int)suf, 0);
  uint sn = (uint)__shfl_down((int)suf, 1);
  if (lane == 63) sn = 0;
  uint c3 = h.w + sn, c2 = c3 + h.z, c1 = c2 + h.y, c0 = c1 + h.x;
  uint binoff, cnt, abv;
  if (c3 >= KTOP)      { binoff = 3; cnt = c3; abv = c3 - h.w; }
  else if (c2 >= KTOP) { binoff = 2; cnt = c2; abv = c2 - h.z; }
  else if (c1 >= KTOP) { binoff = 1; cnt = c1; abv = c1 - h.y; }
  else                 { binoff = 0; cnt = c0; abv = c0 - h.x; }
  uint L0v, cnt0v, abovev;
  if (total < KTOP) {
    L0v = 1u; cnt0v = total; abovev = 0u;
  } else {
    u64 m = __ballot(suf >= KTOP);
    int l = 63 - __clzll(m);
    uint bo = (uint)__shfl((int)binoff, l);
    cnt0v = (uint)__shfl((int)cnt, l);
    abovev = (uint)__shfl((int)abv, l);
    L0v = ((uint)(4 * l) + bo) << 18;
  }
  if (lane == 0) L0cnt[task] = make_uint4(L0v, cnt0v, abovev, total);
}

// ---- K3: distributed collect (B*C1*SEGS blocks, BW-bound streaming filter) ---
__global__ __launch_bounds__(NT) void collect_kernel(
    const uint* __restrict__ keys, const uint4* __restrict__ L0cnt,
    u64* __restrict__ cand, uint* __restrict__ cnts, int N)
{
  int blk = blockIdx.x;
  int task = blk >> 2, seg = blk & (SEGS - 1);
  int tid = threadIdx.x, lane = tid & 63;
  uint4 w0 = L0cnt[task];
  uint L = w0.x, cnt0 = w0.y;
  __shared__ uint sCnt;
  if (tid == 0) sCnt = 0;
  __syncthreads();
  if (cnt0 > CAPC) { if (tid == 0) cnts[blk] = 0; return; }   // slow path in K4

  const uint* krow = keys + (size_t)task * N;
  const uint4* krow4 = reinterpret_cast<const uint4*>(krow);
  int nv = N >> 2;
  int per = (nv + SEGS - 1) >> 2;
  int s4 = seg * per, e4 = min(nv, s4 + per);
  u64* myc = cand + ((size_t)task * SEGS + seg) * SEGCAP;

  for (int i = s4 + tid; i < e4; i += NT) {
    uint4 kv = krow4[i];
    int base = i << 2;
#pragma unroll
    for (int comp = 0; comp < 4; ++comp) {
      uint k = (comp == 0) ? kv.x : (comp == 1) ? kv.y : (comp == 2) ? kv.z : kv.w;
      bool f = (k >= L);
      u64 m = __ballot(f);
      if (m) {
        uint nb = (uint)__popcll(m);
        uint wb = 0;
        if (lane == 0) wb = atomicAdd(&sCnt, nb);
        wb = (uint)__shfl((int)wb, 0);
        if (f) {
          uint pos = wb + (uint)__popcll(m & ((1ULL << lane) - 1ULL));
          if (pos < SEGCAP) myc[pos] = ((u64)k << 32) | (uint)(base + comp);
        }
      }
    }
  }
  if (seg == SEGS - 1) {
    for (int n0 = nv << 2; n0 < N; n0 += NT) {
      int n = n0 + tid;
      uint k = (n < N) ? krow[n] : 0u;
      bool f = (k >= L) && (n < N);
      u64 m = __ballot(f);
      if (m) {
        uint nb = (uint)__popcll(m);
        uint wb = 0;
        if (lane == 0) wb = atomicAdd(&sCnt, nb);
        wb = (uint)__shfl((int)wb, 0);
        if (f) {
          uint pos = wb + (uint)__popcll(m & ((1ULL << lane) - 1ULL));
          if (pos < SEGCAP) myc[pos] = ((u64)k << 32) | (uint)n;
        }
      }
    }
  }
  __syncthreads();
  if (tid == 0) cnts[blk] = sCnt;      // actual (uncapped) count
}

// ---- K4: narrow -> exact rank-sort -> bitmask NMS -> output ------------------
__global__ __launch_bounds__(NT) void final_kernel(
    const uint* __restrict__ keys, const uint4* __restrict__ L0cnt,
    const u64* __restrict__ candg, const uint* __restrict__ cnts,
    const float* __restrict__ scores, const double* __restrict__ lse,
    const float4* __restrict__ boxesws, const float* __restrict__ nms_th_p,
    float* __restrict__ out, int B, int N)
{
  int task = blockIdx.x;
  int b = task / C1, c = task - b * C1;
  int tid = threadIdx.x, lane = tid & 63;
  const uint* krow = keys + (size_t)task * N;
  const uint4* krow4 = reinterpret_cast<const uint4*>(krow);
  int nv = N >> 2;

  __shared__ u64 cand[CAPC];             // 24 KB
  __shared__ uint histB[256];
  __shared__ uint scq[SEGS];
  __shared__ int si[CAP];
  __shared__ u64 skey[CAP];
  __shared__ u64 skid[CAP];
  __shared__ float bl[KTOP], bt[KTOP], br_[KTOP], bb_[KTOP];
  __shared__ double sarea[KTOP];
  __shared__ u64 smask[MROWS][4];
  __shared__ u64 saliveW[4];
  __shared__ uint sCnt, sCnt2, sCur, sAbove, sPref;

  uint4 w0 = L0cnt[task];
  uint cnt0 = w0.y;
  if (tid < SEGS) scq[tid] = cnts[task * SEGS + tid];
  if (tid == 0) { sCnt = 0; sCnt2 = 0; }
  __syncthreads();

  bool slow = (cnt0 > CAPC) ||
              (scq[0] > SEGCAP) || (scq[1] > SEGCAP) ||
              (scq[2] > SEGCAP) || (scq[3] > SEGCAP);

  uint cnt;
  if (!slow) {
    // ---------- fast path: stage precollected candidates
    uint off1 = scq[0], off2 = off1 + scq[1], off3 = off2 + scq[2];
    cnt = off3 + scq[3];
    const u64* cg = candg + (size_t)task * SEGS * SEGCAP;
    for (int j = tid; j < (int)scq[0]; j += NT) cand[j] = cg[j];
    for (int j = tid; j < (int)scq[1]; j += NT) cand[off1 + j] = cg[SEGCAP + j];
    for (int j = tid; j < (int)scq[2]; j += NT) cand[off2 + j] = cg[2 * SEGCAP + j];
    for (int j = tid; j < (int)scq[3]; j += NT) cand[off3 + j] = cg[3 * SEGCAP + j];
    __syncthreads();
  } else {
    // ---------- slow path (rare): refine threshold on q-bits, then collect
    uint L = w0.x, above = w0.z, cur = cnt0;
    uint pref = L >> 18, rank = KTOP - above;
    int shift = 18;
    while (cur > CAPC && shift > 2) {
      shift -= 8;                        // 10, then 2
      if (tid < 256) histB[tid] = 0;
      __syncthreads();
      for (int i = tid; i < nv; i += NT) {
        uint4 kv = krow4[i];
        if ((kv.x >> (shift + 8)) == pref) atomicAdd(&histB[(kv.x >> shift) & 255u], 1u);
        if ((kv.y >> (shift + 8)) == pref) atomicAdd(&histB[(kv.y >> shift) & 255u], 1u);
        if ((kv.z >> (shift + 8)) == pref) atomicAdd(&histB[(kv.z >> shift) & 255u], 1u);
        if ((kv.w >> (shift + 8)) == pref) atomicAdd(&histB[(kv.w >> shift) & 255u], 1u);
      }
      for (int n0 = nv << 2; n0 < N; n0 += NT) {
        int n = n0 + tid;
        if (n < N) {
          uint k = krow[n];
          if ((k >> (shift + 8)) == pref) atomicAdd(&histB[(k >> shift) & 255u], 1u);
        }
      }
      __syncthreads();
      if (tid == 0) {
        uint cum = 0; int bin = 255;
        for (int jj = 255; jj >= 0; --jj) { cum += histB[jj]; if (cum >= rank) { bin = jj; break; } }
        sCur = above + cum;
        sAbove = above + cum - histB[bin];
        sPref = (pref << 8) | (uint)bin;
      }
      __syncthreads();
      cur = sCur; above = sAbove; pref = sPref; rank = KTOP - above;
      L = pref << shift;
      __syncthreads();
    }
    for (int i = tid; i < nv; i += NT) {
      uint4 kv = krow4[i];
      int base = i << 2;
#pragma unroll
      for (int comp = 0; comp < 4; ++comp) {
        uint k = (comp == 0) ? kv.x : (comp == 1) ? kv.y : (comp == 2) ? kv.z : kv.w;
        bool f = (k >= L);
        u64 m = __ballot(f);
        if (m) {
          uint nb = (uint)__popcll(m);
          uint wb = 0;
          if (lane == 0) wb = atomicAdd(&sCnt, nb);
          wb = (uint)__shfl((int)wb, 0);
          if (f) {
            uint pos = wb + (uint)__popcll(m & ((1ULL << lane) - 1ULL));
            if (pos < CAPC) cand[pos] = ((u64)k << 32) | (uint)(base + comp);
          }
        }
      }
    }
    for (int n0 = nv << 2; n0 < N; n0 += NT) {
      int n = n0 + tid;
      uint k = (n < N) ? krow[n] : 0u;
      bool f = (k >= L) && (n < N);
      u64 m = __ballot(f);
      if (m) {
        uint nb = (uint)__popcll(m);
        uint wb = 0;
        if (lane == 0) wb = atomicAdd(&sCnt, nb);
        wb = (uint)__shfl((int)wb, 0);
        if (f) {
          uint pos = wb + (uint)__popcll(m & ((1ULL << lane) - 1ULL));
          if (pos < CAPC) cand[pos] = ((u64)k << 32) | (uint)n;
        }
      }
    }
    __syncthreads();
    cnt = min(sCnt, (uint)CAPC);
  }

  // ---------- narrow candidate list to <= CAP (LDS-resident radix walk)
  uint cntF;
  if (cnt <= CAP) {
    for (int p = tid; p < (int)cnt; p += NT) si[p] = (int)(uint)cand[p];
    __syncthreads();
    cntF = cnt;
  } else {
    uint pref2 = 0, above2 = 0, rank2 = KTOP, cur2 = cnt;
    int sh = 32;
    while (cur2 > CAP && sh > 0) {
      sh -= 8;
      if (tid < 256) histB[tid] = 0;
      __syncthreads();
      for (int p = tid; p < (int)cnt; p += NT) {
        uint k = (uint)(cand[p] >> 32);
        if (sh == 24 || (k >> (sh + 8)) == pref2) atomicAdd(&histB[(k >> sh) & 255u], 1u);
      }
      __syncthreads();
      if (tid == 0) {
        uint cum = 0; int bin = 255;
        for (int jj = 255; jj >= 0; --jj) { cum += histB[jj]; if (cum >= rank2) { bin = jj; break; } }
        sCur = above2 + cum;
        sAbove = above2 + cum - histB[bin];
        sPref = (sh == 24) ? (uint)bin : ((pref2 << 8) | (uint)bin);
      }
      __syncthreads();
      cur2 = sCur; above2 = sAbove; pref2 = sPref; rank2 = KTOP - above2;
      __syncthreads();
    }
    uint T = pref2 << sh;
    for (int p = tid; p < (int)cnt; p += NT) {
      u64 e = cand[p];
      uint k = (uint)(e >> 32);
      if (k >= T) { uint q = atomicAdd(&sCnt2, 1u); if (q < CAP) si[q] = (int)(uint)e; }
    }
    __syncthreads();
    cntF = min(sCnt2, (uint)CAP);
  }

  int valid_cnt = (int)min(cntF, (uint)KTOP);

  // ---------- gather exact f64 scores; pad; rank-sort (one barrier)
  {
    int p = tid;
    if (p < (int)cntF) {
      int n = si[p];
      double s = (double)scores[((size_t)b * NCLS + (c + 1)) * N + n] - lse[(size_t)b * N + n];
      skey[p] = flip64(s);
    } else {
      skey[p] = 0ULL;
      si[p] = 0x40000000 + p;
    }
  }
  __syncthreads();
  {
    u64 kp = skey[tid];
    int ip = si[tid];
    int r = 0;
#pragma unroll 4
    for (int jj = 0; jj < CAP; ++jj) {
      u64 kj = skey[jj];
      int ij = si[jj];
      r += ((kj > kp) || (kj == kp && ij < ip)) ? 1 : 0;
    }
    skid[r] = kp;
    if (tid < (int)cntF && r < KTOP) {
      float4 bx = boxesws[(size_t)b * N + ip];
      bl[r] = bx.x; bt[r] = bx.y; br_[r] = bx.z; bb_[r] = bx.w;
      double w = fmax((double)bx.z - (double)bx.x, 0.0);
      double h = fmax((double)bx.w - (double)bx.y, 0.0);
      sarea[r] = w * h;
    }
  }
  __syncthreads();

  double nth = (double)(*nms_th_p);

  // ---------- 208x4-word suppression bitmask
  for (int u = tid; u < MROWS * 4; u += NT) {
    int i = u >> 2, w = u & 3;
    u64 m = 0;
    if (i < valid_cnt) {
      int j0 = max(i + 1, w * 64);
      int j1 = min(valid_cnt, w * 64 + 64);
      double li = (double)bl[i], ti = (double)bt[i];
      double ri = (double)br_[i], bi = (double)bb_[i];
      double ai = sarea[i];
      for (int jj = j0; jj < j1; ++jj) {
        double xx1 = fmax(li, (double)bl[jj]);
        double yy1 = fmax(ti, (double)bt[jj]);
        double xx2 = fmin(ri, (double)br_[jj]);
        double yy2 = fmin(bi, (double)bb_[jj]);
        double ww = fmax(xx2 - xx1, 0.0), hh = fmax(yy2 - yy1, 0.0);
        double inter = ww * hh;
        double iou = inter / (ai + sarea[jj] - inter + 1e-9);
        if (iou >= nth) m |= 1ULL << (jj - w * 64);
      }
    }
    smask[i][w] = m;
  }
  __syncthreads();

  // ---------- greedy resolve: wave 0, masks in registers, pure VALU chain
  if (tid < 64) {
    int row = lane >> 2, col = lane & 3;
#define LOADM(cc) u64 M##cc = smask[(cc) * 16 + row][col];
    LOADM(0) LOADM(1) LOADM(2) LOADM(3) LOADM(4) LOADM(5) LOADM(6)
    LOADM(7) LOADM(8) LOADM(9) LOADM(10) LOADM(11) LOADM(12)
#undef LOADM
    int vc = valid_cnt;
    u64 aw0, aw1, aw2, aw3;
    {
      int n0 = vc, n1 = vc - 64, n2 = vc - 128, n3 = vc - 192;
      aw0 = (n0 >= 64) ? ~0ULL : ((n0 > 0) ? ((1ULL << n0) - 1) : 0ULL);
      aw1 = (n1 >= 64) ? ~0ULL : ((n1 > 0) ? ((1ULL << n1) - 1) : 0ULL);
      aw2 = (n2 >= 64) ? ~0ULL : ((n2 > 0) ? ((1ULL << n2) - 1) : 0ULL);
      aw3 = (n3 >= 64) ? ~0ULL : ((n3 > 0) ? ((1ULL << n3) - 1) : 0ULL);
    }
    u64 kp0 = 0, kp1 = 0, kp2 = 0, kp3 = 0;
#define GREEDY_CHUNK(cc, AW, KP) { \
    uint fld = (uint)((AW >> (((cc) & 3) * 16)) & 0xFFFFULL); \
    while (fld) { \
      int bi = __ffs(fld) - 1; \
      int slot = bi << 2; \
      u64 mw0 = __shfl(M##cc, slot); \
      u64 mw1 = __shfl(M##cc, slot + 1); \
      u64 mw2 = __shfl(M##cc, slot + 2); \
      u64 mw3 = __shfl(M##cc, slot + 3); \
      aw0 &= ~mw0; aw1 &= ~mw1; aw2 &= ~mw2; aw3 &= ~mw3; \
      KP |= 1ULL << (((cc) & 3) * 16 + bi); \
      fld = ((uint)((AW >> (((cc) & 3) * 16)) & 0xFFFFULL)) & (uint)(0xFFFFu << (bi + 1)); \
    } }
    GREEDY_CHUNK(0, aw0, kp0) GREEDY_CHUNK(1, aw0, kp0)
    GREEDY_CHUNK(2, aw0, kp0) GREEDY_CHUNK(3, aw0, kp0)
    GREEDY_CHUNK(4, aw1, kp1) GREEDY_CHUNK(5, aw1, kp1)
    GREEDY_CHUNK(6, aw1, kp1) GREEDY_CHUNK(7, aw1, kp1)
    GREEDY_CHUNK(8, aw2, kp2) GREEDY_CHUNK(9, aw2, kp2)
    GREEDY_CHUNK(10, aw2, kp2) GREEDY_CHUNK(11, aw2, kp2)
    GREEDY_CHUNK(12, aw3, kp3)
#undef GREEDY_CHUNK
    if (lane == 0) { saliveW[0] = kp0; saliveW[1] = kp1; saliveW[2] = kp2; saliveW[3] = kp3; }
  }
  __syncthreads();

  // ---------- outputs: boxes | labels | scores | keep
  size_t M = (size_t)C1 * KTOP;
  float* out_boxes  = out;
  float* out_labels = out + (size_t)B * M * 4;
  float* out_scores = out_labels + (size_t)B * M;
  float* out_keep   = out_scores + (size_t)B * M;
  if (tid < KTOP) {
    size_t slot = ((size_t)b * C1 + c) * KTOP + tid;
    bool kept = (tid < valid_cnt) && ((saliveW[tid >> 6] >> (tid & 63)) & 1ULL);
    float4 bx = kept ? make_float4(bl[tid], bt[tid], br_[tid], bb_[tid])
                     : make_float4(0.f, 0.f, 0.f, 0.f);
    reinterpret_cast<float4*>(out_boxes)[slot] = bx;
    out_labels[slot] = kept ? (float)(c + 1) : 0.0f;
    out_scores[slot] = kept ? (float)exp(unflip64(skid[tid])) : 0.0f;
    out_keep[slot]   = kept ? 1.0f : 0.0f;
  }
}

extern "C" void kernel_launch(void* const* d_in, const int* in_sizes, int n_in,
                              void* d_out, int out_size, void* d_ws, size_t ws_size,
                              hipStream_t stream) {
  const float* bboxes   = (const float*)d_in[0];   // [B,4,N]
  const float* scores   = (const float*)d_in[1];   // [B,21,N]
  const float* dboxes   = (const float*)d_in[2];   // [1,N,4]
  const float* conf_th  = (const float*)d_in[3];   // [20]
  const float* nms_th   = (const float*)d_in[4];   // scalar
  const float* scale_xy = (const float*)d_in[6];   // scalar
  const float* scale_wh = (const float*)d_in[7];   // scalar

  int N = in_sizes[2] / 4;
  int B = in_sizes[0] / (4 * N);

  // ws layout: lse f64 | boxes float4 | keys u32 | ghist u32 | L0cnt uint4 | cand u64 | cnts u32
  char* ws = (char*)d_ws;
  size_t off = 0;
  double* lse     = (double*)(ws + off); off += (size_t)B * N * 8;
  float4* boxesws = (float4*)(ws + off); off += (size_t)B * N * 16;
  uint*   keys    = (uint*)  (ws + off); off += (size_t)B * C1 * N * 4;
  uint*   ghist   = (uint*)  (ws + off); off += (size_t)B * C1 * 256 * 4;
  uint4*  L0cnt   = (uint4*) (ws + off); off += (size_t)B * C1 * 16;
  u64*    cand    = (u64*)   (ws + off); off += (size_t)B * C1 * SEGS * SEGCAP * 8;
  uint*   cnts    = (uint*)  (ws + off);

  hipMemsetAsync(ghist, 0, (size_t)B * C1 * 256 * 4, stream);

  int perblk = (N + NSPLIT - 1) / NSPLIT;
  prep_kernel<<<B * NSPLIT, NT, 0, stream>>>(
      bboxes, scores, dboxes, conf_th, scale_xy, scale_wh,
      boxesws, lse, keys, ghist, B, N, perblk);

  walk_kernel<<<B * C1, 64, 0, stream>>>(ghist, L0cnt);

  collect_kernel<<<B * C1 * SEGS, NT, 0, stream>>>(keys, L0cnt, cand, cnts, N);

  final_kernel<<<B * C1, NT, 0, stream>>>(
      keys, L0cnt, cand, cnts, scores, lse, boxesws, nms_th, (float*)d_out, B, N);
}

// Round 7
// 154.403 us; speedup vs baseline: 1.1981x; 1.0335x over previous
//
#include <hip/hip_runtime.h>
#include <math.h>

typedef unsigned int uint;
typedef unsigned long long u64;

#define NT 256
#define KTOP 200
#define CAP 256      // final candidate cap == NT (rank-sort)
#define CAPC 3072    // LDS candidate-list cap (final kernel)
#define SEGS 4       // collect segments per task
#define SEGCAP 1024  // per-segment candidate cap in global
#define NCLS 21
#define C1 20
#define MROWS 208
#define NSPLIT 32    // prep blocks per batch image

__device__ __forceinline__ u64 flip64(double d) {
  u64 u = (u64)__double_as_longlong(d);
  return (u & 0x8000000000000000ULL) ? ~u : (u | 0x8000000000000000ULL);
}

__device__ __forceinline__ double unflip64(u64 k) {
  u64 u = (k & 0x8000000000000000ULL) ? (k ^ 0x8000000000000000ULL) : ~k;
  return __longlong_as_double((long long)u);
}

// monotone fixed-point key for s = log prob (s <= 0); 26-bit, 0 = invalid
__device__ __forceinline__ uint q_key(float sf) {
  float qf = (sf + 16.0f) * 4194304.0f;          // *2^22
  qf = fmaxf(fminf(qf, 67108863.0f), 1.0f);
  return (uint)qf;
}

// parallel 256-bin suffix-scan walk: finds bin = max j with S[j] >= rank.
// res[0]=bin, res[1]=S[bin], res[2]=hist[bin]. All threads must call.
__device__ __forceinline__ void par_walk(const uint* hist, uint* scan, u64* wm,
                                         uint* res, uint rank, int tid) {
  scan[tid] = hist[tid];
  __syncthreads();
#pragma unroll
  for (int off = 1; off < 256; off <<= 1) {
    uint v = scan[tid];
    uint a = (tid + off < 256) ? scan[tid + off] : 0u;
    __syncthreads();
    scan[tid] = v + a;
    __syncthreads();
  }
  u64 m = __ballot(scan[tid] >= rank);
  if ((tid & 63) == 0) wm[tid >> 6] = m;
  __syncthreads();
  if (tid == 0) {
    int bin = 0;
    for (int w = 3; w >= 0; --w) {
      if (wm[w]) { bin = w * 64 + (63 - __clzll(wm[w])); break; }
    }
    res[0] = (uint)bin;
    res[1] = scan[bin];
    res[2] = hist[bin];
  }
  __syncthreads();
}

// ---- K1: decode boxes + f64 LSE + fixed-point keys + fused 256-bin hist ----
__global__ __launch_bounds__(NT) void prep_kernel(
    const float* __restrict__ bboxes,   // [B,4,N]
    const float* __restrict__ scores,   // [B,21,N]
    const float* __restrict__ dboxes,   // [N,4]
    const float* __restrict__ conf_th,  // [20]
    const float* __restrict__ scale_xy_p,
    const float* __restrict__ scale_wh_p,
    float4* __restrict__ boxes_out,     // [B*N]
    double* __restrict__ lse_out,       // [B*N]
    uint*  __restrict__ keys_out,       // [B,20,N]
    uint*  __restrict__ ghist,          // [B*20,256]
    int B, int N, int perblk)
{
  __shared__ double s_logth[C1];
  __shared__ uint lhist[C1 * 256];
  int tid = threadIdx.x;
  if (tid < C1) s_logth[tid] = log((double)conf_th[tid]);
  for (int i = tid; i < C1 * 256; i += NT) lhist[i] = 0;
  __syncthreads();

  int b = blockIdx.x / NSPLIT, j = blockIdx.x - (blockIdx.x / NSPLIT) * NSPLIT;
  int s0 = j * perblk, e0 = min(N, s0 + perblk);
  float sxy = *scale_xy_p, swh = *scale_wh_p;

  for (int n = s0 + tid; n < e0; n += NT) {
    int gid = b * N + n;
    const float* bb = bboxes + (size_t)b * 4 * N + n;
    float bx = bb[0];
    float by = bb[(size_t)N];
    float bw = bb[2 * (size_t)N];
    float bh = bb[3 * (size_t)N];
    float4 d = reinterpret_cast<const float4*>(dboxes)[n];
    float x = sxy * bx * d.z + d.x;
    float y = sxy * by * d.w + d.y;
    float w = expf(swh * bw) * d.z;
    float h = expf(swh * bh) * d.w;
    boxes_out[gid] = make_float4(x - 0.5f * w, y - 0.5f * h, x + 0.5f * w, y + 0.5f * h);

    const float* sc = scores + (size_t)b * NCLS * N + n;
    float v[NCLS];
    float mx = -INFINITY;
#pragma unroll
    for (int c = 0; c < NCLS; ++c) { v[c] = sc[(size_t)c * N]; mx = fmaxf(mx, v[c]); }
    double sum = 0.0;
#pragma unroll
    for (int c = 0; c < NCLS; ++c) sum += exp((double)(v[c] - mx));
    double lse = (double)mx + log(sum);
    lse_out[gid] = lse;

#pragma unroll
    for (int c = 0; c < C1; ++c) {
      double s = (double)v[c + 1] - lse;
      uint key = 0;
      if (s > s_logth[c]) key = q_key((float)s);
      keys_out[((size_t)b * C1 + c) * N + n] = key;
      if (key) atomicAdd(&lhist[c * 256 + (key >> 18)], 1u);
    }
  }
  __syncthreads();
  for (int i = tid; i < C1 * 256; i += NT) {
    uint v = lhist[i];
    if (v) atomicAdd(&ghist[((size_t)b * C1 + (i >> 8)) * 256 + (i & 255)], v);
  }
}

// ---- K2: inline walk + distributed collect (B*C1*SEGS blocks) ---------------
__global__ __launch_bounds__(NT) void collect_kernel(
    const uint* __restrict__ keys, const uint* __restrict__ ghist,
    uint4* __restrict__ L0cnt, u64* __restrict__ cand, uint* __restrict__ cnts,
    int N)
{
  int blk = blockIdx.x;
  int task = blk >> 2, seg = blk & (SEGS - 1);
  int tid = threadIdx.x, lane = tid & 63;
  __shared__ uint sL, sCnt0, sCnt;

  if (tid < 64) {
    uint4 h = reinterpret_cast<const uint4*>(ghist + (size_t)task * 256)[tid];
    uint s = h.x + h.y + h.z + h.w;
    uint suf = s;
#pragma unroll
    for (int off = 1; off < 64; off <<= 1) {
      uint o = (uint)__shfl_down((int)suf, off);
      if (lane + off < 64) suf += o;
    }
    uint total = (uint)__shfl((int)suf, 0);
    uint sn = (uint)__shfl_down((int)suf, 1);
    if (lane == 63) sn = 0;
    uint c3 = h.w + sn, c2 = c3 + h.z, c1 = c2 + h.y, c0 = c1 + h.x;
    uint binoff, cnt, abv;
    if (c3 >= KTOP)      { binoff = 3; cnt = c3; abv = c3 - h.w; }
    else if (c2 >= KTOP) { binoff = 2; cnt = c2; abv = c2 - h.z; }
    else if (c1 >= KTOP) { binoff = 1; cnt = c1; abv = c1 - h.y; }
    else                 { binoff = 0; cnt = c0; abv = c0 - h.x; }
    uint L0v, cnt0v, abovev;
    if (total < KTOP) {
      L0v = 1u; cnt0v = total; abovev = 0u;
    } else {
      u64 m = __ballot(suf >= KTOP);
      int l = 63 - __clzll(m);
      uint bo = (uint)__shfl((int)binoff, l);
      cnt0v = (uint)__shfl((int)cnt, l);
      abovev = (uint)__shfl((int)abv, l);
      L0v = ((uint)(4 * l) + bo) << 18;
    }
    if (lane == 0) {
      sL = L0v; sCnt0 = cnt0v;
      if (seg == 0) L0cnt[task] = make_uint4(L0v, cnt0v, abovev, total);
    }
  }
  if (tid == NT - 1) sCnt = 0;
  __syncthreads();

  uint L = sL, cnt0 = sCnt0;
  if (cnt0 > CAPC) { if (tid == 0) cnts[blk] = 0; return; }   // slow path in K3

  const uint* krow = keys + (size_t)task * N;
  const uint4* krow4 = reinterpret_cast<const uint4*>(krow);
  int nv = N >> 2;
  int per = (nv + SEGS - 1) >> 2;
  int s4 = seg * per, e4 = min(nv, s4 + per);
  u64* myc = cand + ((size_t)task * SEGS + seg) * SEGCAP;

  for (int i = s4 + tid; i < e4; i += NT) {
    uint4 kv = krow4[i];
    int base = i << 2;
#pragma unroll
    for (int comp = 0; comp < 4; ++comp) {
      uint k = (comp == 0) ? kv.x : (comp == 1) ? kv.y : (comp == 2) ? kv.z : kv.w;
      bool f = (k >= L);
      u64 m = __ballot(f);
      if (m) {
        uint nb = (uint)__popcll(m);
        uint wb = 0;
        if (lane == 0) wb = atomicAdd(&sCnt, nb);
        wb = (uint)__shfl((int)wb, 0);
        if (f) {
          uint pos = wb + (uint)__popcll(m & ((1ULL << lane) - 1ULL));
          if (pos < SEGCAP) myc[pos] = ((u64)k << 32) | (uint)(base + comp);
        }
      }
    }
  }
  if (seg == SEGS - 1) {
    for (int n0 = nv << 2; n0 < N; n0 += NT) {
      int n = n0 + tid;
      uint k = (n < N) ? krow[n] : 0u;
      bool f = (k >= L) && (n < N);
      u64 m = __ballot(f);
      if (m) {
        uint nb = (uint)__popcll(m);
        uint wb = 0;
        if (lane == 0) wb = atomicAdd(&sCnt, nb);
        wb = (uint)__shfl((int)wb, 0);
        if (f) {
          uint pos = wb + (uint)__popcll(m & ((1ULL << lane) - 1ULL));
          if (pos < SEGCAP) myc[pos] = ((u64)k << 32) | (uint)n;
        }
      }
    }
  }
  __syncthreads();
  if (tid == 0) cnts[blk] = sCnt;      // actual (uncapped) count
}

// ---- K3: narrow (parallel walks) -> rank-sort -> bitmask NMS -> output ------
__global__ __launch_bounds__(NT) void final_kernel(
    const uint* __restrict__ keys, const uint4* __restrict__ L0cnt,
    const u64* __restrict__ candg, const uint* __restrict__ cnts,
    const float* __restrict__ scores, const double* __restrict__ lse,
    const float4* __restrict__ boxesws, const float* __restrict__ nms_th_p,
    float* __restrict__ out, int B, int N)
{
  int task = blockIdx.x;
  int b = task / C1, c = task - b * C1;
  int tid = threadIdx.x, lane = tid & 63;
  const uint* krow = keys + (size_t)task * N;
  const uint4* krow4 = reinterpret_cast<const uint4*>(krow);
  int nv = N >> 2;

  __shared__ u64 cand[CAPC];             // 24 KB
  __shared__ uint histB[256];
  __shared__ uint scanB[256];
  __shared__ u64 wmB[4];
  __shared__ uint res3[4];
  __shared__ uint scq[SEGS];
  __shared__ int si[CAP];
  __shared__ u64 skey[CAP];
  __shared__ u64 skid[CAP];
  __shared__ float bl[KTOP], bt[KTOP], br_[KTOP], bb_[KTOP];
  __shared__ double sarea[KTOP];
  __shared__ u64 smask[MROWS][4];
  __shared__ u64 saliveW[4];
  __shared__ uint sCnt, sCnt2;

  uint4 w0 = L0cnt[task];
  uint cnt0 = w0.y;
  if (tid < SEGS) scq[tid] = cnts[task * SEGS + tid];
  if (tid == 0) { sCnt = 0; sCnt2 = 0; }
  __syncthreads();
  uint sum4 = scq[0] + scq[1] + scq[2] + scq[3];
  bool slow = (cnt0 > CAPC) || (sum4 > CAPC) ||
              (scq[0] > SEGCAP) || (scq[1] > SEGCAP) ||
              (scq[2] > SEGCAP) || (scq[3] > SEGCAP);

  // state: pref covers bits 25..(sh+8); above = #keys in bins strictly above;
  // rank = KTOP - above (rank within boundary bin)
  uint cnt, pref = w0.x >> 18, above = w0.z, rank = KTOP - w0.z;
  int sh = 10;

  if (!slow) {
    uint off1 = scq[0], off2 = off1 + scq[1], off3 = off2 + scq[2];
    cnt = sum4;
    const u64* cg = candg + (size_t)task * SEGS * SEGCAP;
    for (int j = tid; j < (int)scq[0]; j += NT) cand[j] = cg[j];
    for (int j = tid; j < (int)scq[1]; j += NT) cand[off1 + j] = cg[SEGCAP + j];
    for (int j = tid; j < (int)scq[2]; j += NT) cand[off2 + j] = cg[2 * SEGCAP + j];
    for (int j = tid; j < (int)scq[3]; j += NT) cand[off3 + j] = cg[3 * SEGCAP + j];
    __syncthreads();
  } else {
    // rare: refine threshold over the full row until count <= CAPC
    uint Lrow, cur;
    while (true) {
      histB[tid] = 0;
      __syncthreads();
      for (int i = tid; i < nv; i += NT) {
        uint4 kv = krow4[i];
        if ((kv.x >> (sh + 8)) == pref) atomicAdd(&histB[(kv.x >> sh) & 255u], 1u);
        if ((kv.y >> (sh + 8)) == pref) atomicAdd(&histB[(kv.y >> sh) & 255u], 1u);
        if ((kv.z >> (sh + 8)) == pref) atomicAdd(&histB[(kv.z >> sh) & 255u], 1u);
        if ((kv.w >> (sh + 8)) == pref) atomicAdd(&histB[(kv.w >> sh) & 255u], 1u);
      }
      for (int n0 = nv << 2; n0 < N; n0 += NT) {
        int n = n0 + tid;
        if (n < N) {
          uint k = krow[n];
          if ((k >> (sh + 8)) == pref) atomicAdd(&histB[(k >> sh) & 255u], 1u);
        }
      }
      __syncthreads();
      par_walk(histB, scanB, wmB, res3, rank, tid);
      uint bin = res3[0], Sbin = res3[1], hb = res3[2];
      pref = (pref << 8) | bin;
      uint cnt_ge = above + Sbin;
      above = cnt_ge - hb;
      rank = rank - (Sbin - hb);
      Lrow = pref << sh;
      cur = cnt_ge;
      sh -= 8;
      if (cur <= CAPC || sh < 2) break;
    }
    // collect row with k >= Lrow (ballot compaction)
    for (int i = tid; i < nv; i += NT) {
      uint4 kv = krow4[i];
      int base = i << 2;
#pragma unroll
      for (int comp = 0; comp < 4; ++comp) {
        uint k = (comp == 0) ? kv.x : (comp == 1) ? kv.y : (comp == 2) ? kv.z : kv.w;
        bool f = (k >= Lrow);
        u64 m = __ballot(f);
        if (m) {
          uint nb = (uint)__popcll(m);
          uint wb = 0;
          if (lane == 0) wb = atomicAdd(&sCnt, nb);
          wb = (uint)__shfl((int)wb, 0);
          if (f) {
            uint pos = wb + (uint)__popcll(m & ((1ULL << lane) - 1ULL));
            if (pos < CAPC) cand[pos] = ((u64)k << 32) | (uint)(base + comp);
          }
        }
      }
    }
    for (int n0 = nv << 2; n0 < N; n0 += NT) {
      int n = n0 + tid;
      uint k = (n < N) ? krow[n] : 0u;
      bool f = (k >= Lrow) && (n < N);
      u64 m = __ballot(f);
      if (m) {
        uint nb = (uint)__popcll(m);
        uint wb = 0;
        if (lane == 0) wb = atomicAdd(&sCnt, nb);
        wb = (uint)__shfl((int)wb, 0);
        if (f) {
          uint pos = wb + (uint)__popcll(m & ((1ULL << lane) - 1ULL));
          if (pos < CAPC) cand[pos] = ((u64)k << 32) | (uint)n;
        }
      }
    }
    __syncthreads();
    cnt = min(sCnt, (uint)CAPC);
  }

  // ---------- narrow candidate list to <= CAP (all-parallel walks)
  uint cntF;
  bool direct = (cnt <= CAP);
  if (direct) {
    for (int p = tid; p < (int)cnt; p += NT) si[p] = (int)(uint)cand[p];
    __syncthreads();
    cntF = cnt;
  } else {
    uint T = 0;
    bool done = false;
    while (!done && sh >= 2) {
      histB[tid] = 0;
      __syncthreads();
      for (int p = tid; p < (int)cnt; p += NT) {
        uint k = (uint)(cand[p] >> 32);
        if ((k >> (sh + 8)) == pref) atomicAdd(&histB[(k >> sh) & 255u], 1u);
      }
      __syncthreads();
      par_walk(histB, scanB, wmB, res3, rank, tid);
      uint bin = res3[0], Sbin = res3[1], hb = res3[2];
      pref = (pref << 8) | bin;
      uint cnt_ge = above + Sbin;
      if (cnt_ge <= CAP) { T = pref << sh; done = true; }
      else { above = cnt_ge - hb; rank = rank - (Sbin - hb); }
      sh -= 8;
    }
    if (!done) {
      // last 2 bits: 4 bins
      if (tid < 4) histB[tid] = 0;
      __syncthreads();
      for (int p = tid; p < (int)cnt; p += NT) {
        uint k = (uint)(cand[p] >> 32);
        if ((k >> 2) == pref) atomicAdd(&histB[k & 3u], 1u);
      }
      __syncthreads();
      if (tid == 0) {
        uint cum = 0; int bin = 0;
        for (int j = 3; j >= 0; --j) { cum += histB[j]; if (cum >= rank) { bin = j; break; } }
        res3[0] = (uint)bin;
      }
      __syncthreads();
      T = (pref << 2) | res3[0];
    }
    for (int p = tid; p < (int)cnt; p += NT) {
      u64 e = cand[p];
      uint k = (uint)(e >> 32);
      if (k >= T) { uint q = atomicAdd(&sCnt2, 1u); if (q < CAP) si[q] = (int)(uint)e; }
    }
    __syncthreads();
    cntF = min(sCnt2, (uint)CAP);
  }

  int valid_cnt = (int)min(cntF, (uint)KTOP);

  // ---------- gather exact f64 scores; pad; rank-sort (one barrier)
  {
    int p = tid;
    if (p < (int)cntF) {
      int n = si[p];
      double s = (double)scores[((size_t)b * NCLS + (c + 1)) * N + n] - lse[(size_t)b * N + n];
      skey[p] = flip64(s);
    } else {
      skey[p] = 0ULL;
      si[p] = 0x40000000 + p;
    }
  }
  __syncthreads();
  {
    u64 kp = skey[tid];
    int ip = si[tid];
    int r = 0;
#pragma unroll 4
    for (int jj = 0; jj < CAP; ++jj) {
      u64 kj = skey[jj];
      int ij = si[jj];
      r += ((kj > kp) || (kj == kp && ij < ip)) ? 1 : 0;
    }
    skid[r] = kp;
    if (tid < (int)cntF && r < KTOP) {
      float4 bx = boxesws[(size_t)b * N + ip];
      bl[r] = bx.x; bt[r] = bx.y; br_[r] = bx.z; bb_[r] = bx.w;
      double w = fmax((double)bx.z - (double)bx.x, 0.0);
      double h = fmax((double)bx.w - (double)bx.y, 0.0);
      sarea[r] = w * h;
    }
  }
  __syncthreads();

  double nth = (double)(*nms_th_p);

  // ---------- 208x4-word suppression bitmask
  for (int u = tid; u < MROWS * 4; u += NT) {
    int i = u >> 2, w = u & 3;
    u64 m = 0;
    if (i < valid_cnt) {
      int j0 = max(i + 1, w * 64);
      int j1 = min(valid_cnt, w * 64 + 64);
      double li = (double)bl[i], ti = (double)bt[i];
      double ri = (double)br_[i], bi = (double)bb_[i];
      double ai = sarea[i];
      for (int jj = j0; jj < j1; ++jj) {
        double xx1 = fmax(li, (double)bl[jj]);
        double yy1 = fmax(ti, (double)bt[jj]);
        double xx2 = fmin(ri, (double)br_[jj]);
        double yy2 = fmin(bi, (double)bb_[jj]);
        double ww = fmax(xx2 - xx1, 0.0), hh = fmax(yy2 - yy1, 0.0);
        double inter = ww * hh;
        double iou = inter / (ai + sarea[jj] - inter + 1e-9);
        if (iou >= nth) m |= 1ULL << (jj - w * 64);
      }
    }
    smask[i][w] = m;
  }
  __syncthreads();

  // ---------- greedy resolve: wave 0, masks in registers, pure VALU chain
  if (tid < 64) {
    int row = lane >> 2, col = lane & 3;
#define LOADM(cc) u64 M##cc = smask[(cc) * 16 + row][col];
    LOADM(0) LOADM(1) LOADM(2) LOADM(3) LOADM(4) LOADM(5) LOADM(6)
    LOADM(7) LOADM(8) LOADM(9) LOADM(10) LOADM(11) LOADM(12)
#undef LOADM
    int vc = valid_cnt;
    u64 aw0, aw1, aw2, aw3;
    {
      int n0 = vc, n1 = vc - 64, n2 = vc - 128, n3 = vc - 192;
      aw0 = (n0 >= 64) ? ~0ULL : ((n0 > 0) ? ((1ULL << n0) - 1) : 0ULL);
      aw1 = (n1 >= 64) ? ~0ULL : ((n1 > 0) ? ((1ULL << n1) - 1) : 0ULL);
      aw2 = (n2 >= 64) ? ~0ULL : ((n2 > 0) ? ((1ULL << n2) - 1) : 0ULL);
      aw3 = (n3 >= 64) ? ~0ULL : ((n3 > 0) ? ((1ULL << n3) - 1) : 0ULL);
    }
    u64 kp0 = 0, kp1 = 0, kp2 = 0, kp3 = 0;
#define GREEDY_CHUNK(cc, AW, KP) { \
    uint fld = (uint)((AW >> (((cc) & 3) * 16)) & 0xFFFFULL); \
    while (fld) { \
      int bi = __ffs(fld) - 1; \
      int slot = bi << 2; \
      u64 mw0 = __shfl(M##cc, slot); \
      u64 mw1 = __shfl(M##cc, slot + 1); \
      u64 mw2 = __shfl(M##cc, slot + 2); \
      u64 mw3 = __shfl(M##cc, slot + 3); \
      aw0 &= ~mw0; aw1 &= ~mw1; aw2 &= ~mw2; aw3 &= ~mw3; \
      KP |= 1ULL << (((cc) & 3) * 16 + bi); \
      fld = ((uint)((AW >> (((cc) & 3) * 16)) & 0xFFFFULL)) & (uint)(0xFFFFu << (bi + 1)); \
    } }
    GREEDY_CHUNK(0, aw0, kp0) GREEDY_CHUNK(1, aw0, kp0)
    GREEDY_CHUNK(2, aw0, kp0) GREEDY_CHUNK(3, aw0, kp0)
    GREEDY_CHUNK(4, aw1, kp1) GREEDY_CHUNK(5, aw1, kp1)
    GREEDY_CHUNK(6, aw1, kp1) GREEDY_CHUNK(7, aw1, kp1)
    GREEDY_CHUNK(8, aw2, kp2) GREEDY_CHUNK(9, aw2, kp2)
    GREEDY_CHUNK(10, aw2, kp2) GREEDY_CHUNK(11, aw2, kp2)
    GREEDY_CHUNK(12, aw3, kp3)
#undef GREEDY_CHUNK
    if (lane == 0) { saliveW[0] = kp0; saliveW[1] = kp1; saliveW[2] = kp2; saliveW[3] = kp3; }
  }
  __syncthreads();

  // ---------- outputs: boxes | labels | scores | keep
  size_t M = (size_t)C1 * KTOP;
  float* out_boxes  = out;
  float* out_labels = out + (size_t)B * M * 4;
  float* out_scores = out_labels + (size_t)B * M;
  float* out_keep   = out_scores + (size_t)B * M;
  if (tid < KTOP) {
    size_t slot = ((size_t)b * C1 + c) * KTOP + tid;
    bool kept = (tid < valid_cnt) && ((saliveW[tid >> 6] >> (tid & 63)) & 1ULL);
    float4 bx = kept ? make_float4(bl[tid], bt[tid], br_[tid], bb_[tid])
                     : make_float4(0.f, 0.f, 0.f, 0.f);
    reinterpret_cast<float4*>(out_boxes)[slot] = bx;
    out_labels[slot] = kept ? (float)(c + 1) : 0.0f;
    out_scores[slot] = kept ? (float)exp(unflip64(skid[tid])) : 0.0f;
    out_keep[slot]   = kept ? 1.0f : 0.0f;
  }
}

extern "C" void kernel_launch(void* const* d_in, const int* in_sizes, int n_in,
                              void* d_out, int out_size, void* d_ws, size_t ws_size,
                              hipStream_t stream) {
  const float* bboxes   = (const float*)d_in[0];   // [B,4,N]
  const float* scores   = (const float*)d_in[1];   // [B,21,N]
  const float* dboxes   = (const float*)d_in[2];   // [1,N,4]
  const float* conf_th  = (const float*)d_in[3];   // [20]
  const float* nms_th   = (const float*)d_in[4];   // scalar
  const float* scale_xy = (const float*)d_in[6];   // scalar
  const float* scale_wh = (const float*)d_in[7];   // scalar

  int N = in_sizes[2] / 4;
  int B = in_sizes[0] / (4 * N);

  // ws layout: lse f64 | boxes float4 | keys u32 | ghist u32 | L0cnt uint4 | cand u64 | cnts u32
  char* ws = (char*)d_ws;
  size_t off = 0;
  double* lse     = (double*)(ws + off); off += (size_t)B * N * 8;
  float4* boxesws = (float4*)(ws + off); off += (size_t)B * N * 16;
  uint*   keys    = (uint*)  (ws + off); off += (size_t)B * C1 * N * 4;
  uint*   ghist   = (uint*)  (ws + off); off += (size_t)B * C1 * 256 * 4;
  uint4*  L0cnt   = (uint4*) (ws + off); off += (size_t)B * C1 * 16;
  u64*    cand    = (u64*)   (ws + off); off += (size_t)B * C1 * SEGS * SEGCAP * 8;
  uint*   cnts    = (uint*)  (ws + off);

  hipMemsetAsync(ghist, 0, (size_t)B * C1 * 256 * 4, stream);

  int perblk = (N + NSPLIT - 1) / NSPLIT;
  prep_kernel<<<B * NSPLIT, NT, 0, stream>>>(
      bboxes, scores, dboxes, conf_th, scale_xy, scale_wh,
      boxesws, lse, keys, ghist, B, N, perblk);

  collect_kernel<<<B * C1 * SEGS, NT, 0, stream>>>(
      keys, ghist, L0cnt, cand, cnts, N);

  final_kernel<<<B * C1, NT, 0, stream>>>(
      keys, L0cnt, cand, cnts, scores, lse, boxesws, nms_th, (float*)d_out, B, N);
}

// Round 8
// 142.577 us; speedup vs baseline: 1.2975x; 1.0829x over previous
//
#include <hip/hip_runtime.h>
#include <math.h>

typedef unsigned int uint;
typedef unsigned long long u64;

#define NT 256
#define KTOP 200
#define CAP 256      // final candidate cap == NT (rank-sort)
#define CAPC 3072    // LDS candidate-list cap
#define SEGS 4       // collect segments per task
#define SEGCAP 512   // per-segment candidate cap in global
#define NCLS 21
#define C1 20
#define MROWS 208
#define NSPLIT 32    // prep blocks per batch image

__device__ __forceinline__ u64 flip64(double d) {
  u64 u = (u64)__double_as_longlong(d);
  return (u & 0x8000000000000000ULL) ? ~u : (u | 0x8000000000000000ULL);
}

__device__ __forceinline__ double unflip64(u64 k) {
  u64 u = (k & 0x8000000000000000ULL) ? (k ^ 0x8000000000000000ULL) : ~k;
  return __longlong_as_double((long long)u);
}

// monotone fixed-point key for s = log prob (s <= 0); 26-bit, 0 = invalid
__device__ __forceinline__ uint q_key(float sf) {
  float qf = (sf + 16.0f) * 4194304.0f;          // *2^22
  qf = fmaxf(fminf(qf, 67108863.0f), 1.0f);
  return (uint)qf;
}

// parallel 256-bin suffix-scan walk: bin = max j with S[j] >= rank.
// res[0]=bin, res[1]=S[bin], res[2]=hist[bin]. All threads must call.
__device__ __forceinline__ void par_walk(const uint* hist, uint* scan, u64* wm,
                                         uint* res, uint rank, int tid) {
  scan[tid] = hist[tid];
  __syncthreads();
#pragma unroll
  for (int off = 1; off < 256; off <<= 1) {
    uint v = scan[tid];
    uint a = (tid + off < 256) ? scan[tid + off] : 0u;
    __syncthreads();
    scan[tid] = v + a;
    __syncthreads();
  }
  u64 m = __ballot(scan[tid] >= rank);
  if ((tid & 63) == 0) wm[tid >> 6] = m;
  __syncthreads();
  if (tid == 0) {
    int bin = 0;
    for (int w = 3; w >= 0; --w) {
      if (wm[w]) { bin = w * 64 + (63 - __clzll(wm[w])); break; }
    }
    res[0] = (uint)bin;
    res[1] = scan[bin];
    res[2] = hist[bin];
  }
  __syncthreads();
}

// ---- K1: decode boxes + f64 LSE + fixed-point keys + fused 256-bin hist ----
__global__ __launch_bounds__(NT) void prep_kernel(
    const float* __restrict__ bboxes, const float* __restrict__ scores,
    const float* __restrict__ dboxes, const float* __restrict__ conf_th,
    const float* __restrict__ scale_xy_p, const float* __restrict__ scale_wh_p,
    float4* __restrict__ boxes_out, double* __restrict__ lse_out,
    uint* __restrict__ keys_out, uint* __restrict__ ghist,
    int B, int N, int perblk)
{
  __shared__ double s_logth[C1];
  __shared__ uint lhist[C1 * 256];
  int tid = threadIdx.x;
  if (tid < C1) s_logth[tid] = log((double)conf_th[tid]);
  for (int i = tid; i < C1 * 256; i += NT) lhist[i] = 0;
  __syncthreads();

  int b = blockIdx.x / NSPLIT, j = blockIdx.x - (blockIdx.x / NSPLIT) * NSPLIT;
  int s0 = j * perblk, e0 = min(N, s0 + perblk);
  float sxy = *scale_xy_p, swh = *scale_wh_p;

  for (int n = s0 + tid; n < e0; n += NT) {
    int gid = b * N + n;
    const float* bb = bboxes + (size_t)b * 4 * N + n;
    float bx = bb[0];
    float by = bb[(size_t)N];
    float bw = bb[2 * (size_t)N];
    float bh = bb[3 * (size_t)N];
    float4 d = reinterpret_cast<const float4*>(dboxes)[n];
    float x = sxy * bx * d.z + d.x;
    float y = sxy * by * d.w + d.y;
    float w = expf(swh * bw) * d.z;
    float h = expf(swh * bh) * d.w;
    boxes_out[gid] = make_float4(x - 0.5f * w, y - 0.5f * h, x + 0.5f * w, y + 0.5f * h);

    const float* sc = scores + (size_t)b * NCLS * N + n;
    float v[NCLS];
    float mx = -INFINITY;
#pragma unroll
    for (int c = 0; c < NCLS; ++c) { v[c] = sc[(size_t)c * N]; mx = fmaxf(mx, v[c]); }
    double sum = 0.0;
#pragma unroll
    for (int c = 0; c < NCLS; ++c) sum += exp((double)(v[c] - mx));
    double lse = (double)mx + log(sum);
    lse_out[gid] = lse;

#pragma unroll
    for (int c = 0; c < C1; ++c) {
      double s = (double)v[c + 1] - lse;
      uint key = 0;
      if (s > s_logth[c]) key = q_key((float)s);
      keys_out[((size_t)b * C1 + c) * N + n] = key;
      if (key) atomicAdd(&lhist[c * 256 + (key >> 18)], 1u);
    }
  }
  __syncthreads();
  for (int i = tid; i < C1 * 256; i += NT) {
    uint v = lhist[i];
    if (v) atomicAdd(&ghist[((size_t)b * C1 + (i >> 8)) * 256 + (i & 255)], v);
  }
}

// ---- K2: inline walk + distributed collect (B*C1*SEGS blocks) ---------------
__global__ __launch_bounds__(NT) void collect_kernel(
    const uint* __restrict__ keys, const uint* __restrict__ ghist,
    uint4* __restrict__ L0cnt, u64* __restrict__ cand, uint* __restrict__ cnts,
    int N)
{
  int blk = blockIdx.x;
  int task = blk >> 2, seg = blk & (SEGS - 1);
  int tid = threadIdx.x, lane = tid & 63;
  __shared__ uint sL, sCnt0, sCnt;

  if (tid < 64) {
    uint4 h = reinterpret_cast<const uint4*>(ghist + (size_t)task * 256)[tid];
    uint s = h.x + h.y + h.z + h.w;
    uint suf = s;
#pragma unroll
    for (int off = 1; off < 64; off <<= 1) {
      uint o = (uint)__shfl_down((int)suf, off);
      if (lane + off < 64) suf += o;
    }
    uint total = (uint)__shfl((int)suf, 0);
    uint sn = (uint)__shfl_down((int)suf, 1);
    if (lane == 63) sn = 0;
    uint c3 = h.w + sn, c2 = c3 + h.z, c1 = c2 + h.y, c0 = c1 + h.x;
    uint binoff, cnt, abv;
    if (c3 >= KTOP)      { binoff = 3; cnt = c3; abv = c3 - h.w; }
    else if (c2 >= KTOP) { binoff = 2; cnt = c2; abv = c2 - h.z; }
    else if (c1 >= KTOP) { binoff = 1; cnt = c1; abv = c1 - h.y; }
    else                 { binoff = 0; cnt = c0; abv = c0 - h.x; }
    uint L0v, cnt0v, abovev;
    if (total < KTOP) {
      L0v = 1u; cnt0v = total; abovev = 0u;
    } else {
      u64 m = __ballot(suf >= KTOP);
      int l = 63 - __clzll(m);
      uint bo = (uint)__shfl((int)binoff, l);
      cnt0v = (uint)__shfl((int)cnt, l);
      abovev = (uint)__shfl((int)abv, l);
      L0v = ((uint)(4 * l) + bo) << 18;
    }
    if (lane == 0) {
      sL = L0v; sCnt0 = cnt0v;
      if (seg == 0) L0cnt[task] = make_uint4(L0v, cnt0v, abovev, total);
    }
  }
  if (tid == NT - 1) sCnt = 0;
  __syncthreads();

  uint L = sL, cnt0 = sCnt0;
  if (cnt0 > CAPC) { if (tid == 0) cnts[blk] = 0; return; }   // slow path in F1

  const uint* krow = keys + (size_t)task * N;
  const uint4* krow4 = reinterpret_cast<const uint4*>(krow);
  int nv = N >> 2;
  int per = (nv + SEGS - 1) >> 2;
  int s4 = seg * per, e4 = min(nv, s4 + per);
  u64* myc = cand + ((size_t)task * SEGS + seg) * SEGCAP;

  for (int i = s4 + tid; i < e4; i += NT) {
    uint4 kv = krow4[i];
    int base = i << 2;
#pragma unroll
    for (int comp = 0; comp < 4; ++comp) {
      uint k = (comp == 0) ? kv.x : (comp == 1) ? kv.y : (comp == 2) ? kv.z : kv.w;
      bool f = (k >= L);
      u64 m = __ballot(f);
      if (m) {
        uint nb = (uint)__popcll(m);
        uint wb = 0;
        if (lane == 0) wb = atomicAdd(&sCnt, nb);
        wb = (uint)__shfl((int)wb, 0);
        if (f) {
          uint pos = wb + (uint)__popcll(m & ((1ULL << lane) - 1ULL));
          if (pos < SEGCAP) myc[pos] = ((u64)k << 32) | (uint)(base + comp);
        }
      }
    }
  }
  if (seg == SEGS - 1) {
    for (int n0 = nv << 2; n0 < N; n0 += NT) {
      int n = n0 + tid;
      uint k = (n < N) ? krow[n] : 0u;
      bool f = (k >= L) && (n < N);
      u64 m = __ballot(f);
      if (m) {
        uint nb = (uint)__popcll(m);
        uint wb = 0;
        if (lane == 0) wb = atomicAdd(&sCnt, nb);
        wb = (uint)__shfl((int)wb, 0);
        if (f) {
          uint pos = wb + (uint)__popcll(m & ((1ULL << lane) - 1ULL));
          if (pos < SEGCAP) myc[pos] = ((u64)k << 32) | (uint)n;
        }
      }
    }
  }
  __syncthreads();
  if (tid == 0) cnts[blk] = sCnt;      // actual (uncapped) count
}

// ---- F1: narrow -> gather -> rank-sort -> write sorted top-K to ws ----------
__global__ __launch_bounds__(NT) void topk_kernel(
    const uint* __restrict__ keys, const uint4* __restrict__ L0cnt,
    const u64* __restrict__ candg, const uint* __restrict__ cnts,
    const float* __restrict__ scores, const double* __restrict__ lse,
    const float4* __restrict__ boxesws,
    u64* __restrict__ tkeys, float4* __restrict__ tboxes, uint* __restrict__ tcnt,
    int B, int N)
{
  int task = blockIdx.x;
  int b = task / C1, c = task - b * C1;
  int tid = threadIdx.x, lane = tid & 63;
  const uint* krow = keys + (size_t)task * N;
  const uint4* krow4 = reinterpret_cast<const uint4*>(krow);
  int nv = N >> 2;

  __shared__ u64 cand[CAPC];             // 24 KB
  __shared__ uint histB[256];
  __shared__ uint scanB[256];
  __shared__ u64 wmB[4];
  __shared__ uint res3[4];
  __shared__ uint scq[SEGS];
  __shared__ int si[CAP];
  __shared__ u64 skey[CAP];
  __shared__ uint sCnt, sCnt2;

  uint4 w0 = L0cnt[task];
  uint cnt0 = w0.y;
  if (tid < SEGS) scq[tid] = cnts[task * SEGS + tid];
  if (tid == 0) { sCnt = 0; sCnt2 = 0; }
  __syncthreads();
  bool slow = (cnt0 > CAPC) ||
              (scq[0] > SEGCAP) || (scq[1] > SEGCAP) ||
              (scq[2] > SEGCAP) || (scq[3] > SEGCAP);

  uint cnt, pref = w0.x >> 18, above = w0.z, rank = KTOP - w0.z;
  int sh = 10;

  if (!slow) {
    uint off1 = scq[0], off2 = off1 + scq[1], off3 = off2 + scq[2];
    cnt = off3 + scq[3];
    const u64* cg = candg + (size_t)task * SEGS * SEGCAP;
    for (int j = tid; j < (int)scq[0]; j += NT) cand[j] = cg[j];
    for (int j = tid; j < (int)scq[1]; j += NT) cand[off1 + j] = cg[SEGCAP + j];
    for (int j = tid; j < (int)scq[2]; j += NT) cand[off2 + j] = cg[2 * SEGCAP + j];
    for (int j = tid; j < (int)scq[3]; j += NT) cand[off3 + j] = cg[3 * SEGCAP + j];
    __syncthreads();
  } else {
    // rare: refine threshold over the full row until count <= CAPC
    uint Lrow, cur;
    while (true) {
      histB[tid] = 0;
      __syncthreads();
      for (int i = tid; i < nv; i += NT) {
        uint4 kv = krow4[i];
        if ((kv.x >> (sh + 8)) == pref) atomicAdd(&histB[(kv.x >> sh) & 255u], 1u);
        if ((kv.y >> (sh + 8)) == pref) atomicAdd(&histB[(kv.y >> sh) & 255u], 1u);
        if ((kv.z >> (sh + 8)) == pref) atomicAdd(&histB[(kv.z >> sh) & 255u], 1u);
        if ((kv.w >> (sh + 8)) == pref) atomicAdd(&histB[(kv.w >> sh) & 255u], 1u);
      }
      for (int n0 = nv << 2; n0 < N; n0 += NT) {
        int n = n0 + tid;
        if (n < N) {
          uint k = krow[n];
          if ((k >> (sh + 8)) == pref) atomicAdd(&histB[(k >> sh) & 255u], 1u);
        }
      }
      __syncthreads();
      par_walk(histB, scanB, wmB, res3, rank, tid);
      uint bin = res3[0], Sbin = res3[1], hb = res3[2];
      pref = (pref << 8) | bin;
      uint cnt_ge = above + Sbin;
      above = cnt_ge - hb;
      rank = rank - (Sbin - hb);
      Lrow = pref << sh;
      cur = cnt_ge;
      sh -= 8;
      if (cur <= CAPC || sh < 2) break;
    }
    for (int i = tid; i < nv; i += NT) {
      uint4 kv = krow4[i];
      int base = i << 2;
#pragma unroll
      for (int comp = 0; comp < 4; ++comp) {
        uint k = (comp == 0) ? kv.x : (comp == 1) ? kv.y : (comp == 2) ? kv.z : kv.w;
        bool f = (k >= Lrow);
        u64 m = __ballot(f);
        if (m) {
          uint nb = (uint)__popcll(m);
          uint wb = 0;
          if (lane == 0) wb = atomicAdd(&sCnt, nb);
          wb = (uint)__shfl((int)wb, 0);
          if (f) {
            uint pos = wb + (uint)__popcll(m & ((1ULL << lane) - 1ULL));
            if (pos < CAPC) cand[pos] = ((u64)k << 32) | (uint)(base + comp);
          }
        }
      }
    }
    for (int n0 = nv << 2; n0 < N; n0 += NT) {
      int n = n0 + tid;
      uint k = (n < N) ? krow[n] : 0u;
      bool f = (k >= Lrow) && (n < N);
      u64 m = __ballot(f);
      if (m) {
        uint nb = (uint)__popcll(m);
        uint wb = 0;
        if (lane == 0) wb = atomicAdd(&sCnt, nb);
        wb = (uint)__shfl((int)wb, 0);
        if (f) {
          uint pos = wb + (uint)__popcll(m & ((1ULL << lane) - 1ULL));
          if (pos < CAPC) cand[pos] = ((u64)k << 32) | (uint)n;
        }
      }
    }
    __syncthreads();
    cnt = min(sCnt, (uint)CAPC);
  }

  // narrow candidate list to <= CAP
  uint cntF;
  if (cnt <= CAP) {
    for (int p = tid; p < (int)cnt; p += NT) si[p] = (int)(uint)cand[p];
    __syncthreads();
    cntF = cnt;
  } else {
    uint T = 0;
    bool done = false;
    while (!done && sh >= 2) {
      histB[tid] = 0;
      __syncthreads();
      for (int p = tid; p < (int)cnt; p += NT) {
        uint k = (uint)(cand[p] >> 32);
        if ((k >> (sh + 8)) == pref) atomicAdd(&histB[(k >> sh) & 255u], 1u);
      }
      __syncthreads();
      par_walk(histB, scanB, wmB, res3, rank, tid);
      uint bin = res3[0], Sbin = res3[1], hb = res3[2];
      pref = (pref << 8) | bin;
      uint cnt_ge = above + Sbin;
      if (cnt_ge <= CAP) { T = pref << sh; done = true; }
      else { above = cnt_ge - hb; rank = rank - (Sbin - hb); }
      sh -= 8;
    }
    if (!done) {
      if (tid < 4) histB[tid] = 0;
      __syncthreads();
      for (int p = tid; p < (int)cnt; p += NT) {
        uint k = (uint)(cand[p] >> 32);
        if ((k >> 2) == pref) atomicAdd(&histB[k & 3u], 1u);
      }
      __syncthreads();
      if (tid == 0) {
        uint cum = 0; int bin = 0;
        for (int j = 3; j >= 0; --j) { cum += histB[j]; if (cum >= rank) { bin = j; break; } }
        res3[0] = (uint)bin;
      }
      __syncthreads();
      T = (pref << 2) | res3[0];
    }
    for (int p = tid; p < (int)cnt; p += NT) {
      u64 e = cand[p];
      uint k = (uint)(e >> 32);
      if (k >= T) { uint q = atomicAdd(&sCnt2, 1u); if (q < CAP) si[q] = (int)(uint)e; }
    }
    __syncthreads();
    cntF = min(sCnt2, (uint)CAP);
  }

  // gather exact f64 scores; pad; rank-sort; write sorted keys/boxes to ws
  {
    int p = tid;
    if (p < (int)cntF) {
      int n = si[p];
      double s = (double)scores[((size_t)b * NCLS + (c + 1)) * N + n] - lse[(size_t)b * N + n];
      skey[p] = flip64(s);
    } else {
      skey[p] = 0ULL;
      si[p] = 0x40000000 + p;
    }
  }
  __syncthreads();
  {
    u64 kp = skey[tid];
    int ip = si[tid];
    int r = 0;
#pragma unroll 4
    for (int jj = 0; jj < CAP; ++jj) {
      u64 kj = skey[jj];
      int ij = si[jj];
      r += ((kj > kp) || (kj == kp && ij < ip)) ? 1 : 0;
    }
    if (r < KTOP) {
      tkeys[(size_t)task * KTOP + r] = kp;
      float4 bx = (tid < (int)cntF) ? boxesws[(size_t)b * N + ip]
                                    : make_float4(0.f, 0.f, 0.f, 0.f);
      tboxes[(size_t)task * KTOP + r] = bx;
    }
  }
  if (tid == 0) tcnt[task] = min(cntF, (uint)KTOP);
}

// ---- F2: f32 IoU suppression mask (reference op order) + nibble transpose ---
__global__ __launch_bounds__(NT) void mask_kernel(
    const float4* __restrict__ tboxes, const uint* __restrict__ tcnt,
    const float* __restrict__ nms_th_p, u64* __restrict__ gmaskT)
{
  int task = blockIdx.x;
  int tid = threadIdx.x, lane = tid & 63, wav = tid >> 6;
  __shared__ float sbl[MROWS], sbt[MROWS], sbr[MROWS], sbb[MROWS], sar[MROWS];
  __shared__ u64 smask[MROWS][4];

  int valid = (int)tcnt[task];
  float nth = *nms_th_p;

  if (tid < MROWS) {
    float4 bx = (tid < KTOP) ? tboxes[(size_t)task * KTOP + tid]
                             : make_float4(0.f, 0.f, 0.f, 0.f);
    sbl[tid] = bx.x; sbt[tid] = bx.y; sbr[tid] = bx.z; sbb[tid] = bx.w;
    sar[tid] = fmaxf(bx.z - bx.x, 0.f) * fmaxf(bx.w - bx.y, 0.f);
  }
  __syncthreads();

  for (int u = tid; u < MROWS * 4; u += NT) {
    int i = u >> 2, w = u & 3;
    u64 m = 0;
    if (i < valid) {
      int j0 = max(i + 1, w * 64);
      int j1 = min(valid, w * 64 + 64);
      float li = sbl[i], ti = sbt[i], ri = sbr[i], bi = sbb[i], ai = sar[i];
      for (int jj = j0; jj < j1; ++jj) {
        float xx1 = fmaxf(li, sbl[jj]);
        float yy1 = fmaxf(ti, sbt[jj]);
        float xx2 = fminf(ri, sbr[jj]);
        float yy2 = fminf(bi, sbb[jj]);
        float ww = fmaxf(xx2 - xx1, 0.f), hh = fmaxf(yy2 - yy1, 0.f);
        float inter = ww * hh;
        float iou = inter / (((ai + sar[jj]) - inter) + 1e-9f);
        if (iou >= nth) m |= 1ULL << (jj - w * 64);
      }
    }
    smask[i][w] = m;
  }
  __syncthreads();

  // transpose: lane l's nibble for row r = bits l of the 4 words; 16 rows/u64
  for (int w = wav; w < 13; w += 4) {
    u64 outw = 0;
    int r0 = w * 16;
#pragma unroll
    for (int rr = 0; rr < 16; ++rr) {
      int r = r0 + rr;
      uint nib = (uint)((smask[r][0] >> lane) & 1ULL)
               | ((uint)((smask[r][1] >> lane) & 1ULL) << 1)
               | ((uint)((smask[r][2] >> lane) & 1ULL) << 2)
               | ((uint)((smask[r][3] >> lane) & 1ULL) << 3);
      outw |= (u64)nib << (rr * 4);
    }
    gmaskT[((size_t)task * 13 + w) * 64 + lane] = outw;
  }
}

// ---- F3: 1-wave greedy resolve (in-lane, unrolled) + output -----------------
__global__ __launch_bounds__(64) void resolve_kernel(
    const u64* __restrict__ gmaskT, const u64* __restrict__ tkeys,
    const float4* __restrict__ tboxes, const uint* __restrict__ tcnt,
    float* __restrict__ out, int B)
{
  int task = blockIdx.x;
  int b = task / C1, c = task - b * C1;
  int lane = threadIdx.x;
  int valid = (int)tcnt[task];

  u64 m[13];
#pragma unroll
  for (int w = 0; w < 13; ++w)
    m[w] = gmaskT[((size_t)task * 13 + w) * 64 + lane];

  // alive: bit k of av <-> column (lane + 64k)
  uint av = 0;
#pragma unroll
  for (int k = 0; k < 4; ++k)
    if (lane + 64 * k < valid) av |= 1u << k;

#define STEP(i) { \
    u64 bm = __ballot((lane == ((i) & 63)) && ((av >> ((i) >> 6)) & 1u)); \
    if (bm) av &= ~((uint)((m[(i) >> 4] >> (((i) & 15) * 4)) & 0xFULL)); }
#define S4(i)  STEP(i) STEP((i)+1) STEP((i)+2) STEP((i)+3)
#define S16(i) S4(i) S4((i)+4) S4((i)+8) S4((i)+12)
#define S64(i) S16(i) S16((i)+16) S16((i)+32) S16((i)+48)
  S64(0) S64(64) S64(128) S16(192)
#undef S64
#undef S16
#undef S4
#undef STEP

  size_t M = (size_t)C1 * KTOP;
  float* out_boxes  = out;
  float* out_labels = out + (size_t)B * M * 4;
  float* out_scores = out_labels + (size_t)B * M;
  float* out_keep   = out_scores + (size_t)B * M;

#pragma unroll
  for (int k = 0; k < 4; ++k) {
    int s = lane + 64 * k;
    if (s < KTOP) {
      bool kept = (s < valid) && ((av >> k) & 1u);
      size_t slot = ((size_t)b * C1 + c) * KTOP + s;
      float4 bx = kept ? tboxes[(size_t)task * KTOP + s]
                       : make_float4(0.f, 0.f, 0.f, 0.f);
      reinterpret_cast<float4*>(out_boxes)[slot] = bx;
      out_labels[slot] = kept ? (float)(c + 1) : 0.0f;
      out_scores[slot] = kept ? (float)exp(unflip64(tkeys[(size_t)task * KTOP + s])) : 0.0f;
      out_keep[slot]   = kept ? 1.0f : 0.0f;
    }
  }
}

extern "C" void kernel_launch(void* const* d_in, const int* in_sizes, int n_in,
                              void* d_out, int out_size, void* d_ws, size_t ws_size,
                              hipStream_t stream) {
  const float* bboxes   = (const float*)d_in[0];   // [B,4,N]
  const float* scores   = (const float*)d_in[1];   // [B,21,N]
  const float* dboxes   = (const float*)d_in[2];   // [1,N,4]
  const float* conf_th  = (const float*)d_in[3];   // [20]
  const float* nms_th   = (const float*)d_in[4];   // scalar
  const float* scale_xy = (const float*)d_in[6];   // scalar
  const float* scale_wh = (const float*)d_in[7];   // scalar

  int N = in_sizes[2] / 4;
  int B = in_sizes[0] / (4 * N);

  // ws: lse | boxes | keys | ghist | L0cnt | cand | cnts | tkeys | tboxes | tcnt | gmaskT
  char* ws = (char*)d_ws;
  size_t off = 0;
  double* lse     = (double*)(ws + off); off += (size_t)B * N * 8;
  float4* boxesws = (float4*)(ws + off); off += (size_t)B * N * 16;
  uint*   keys    = (uint*)  (ws + off); off += (size_t)B * C1 * N * 4;
  uint*   ghist   = (uint*)  (ws + off); off += (size_t)B * C1 * 256 * 4;
  uint4*  L0cnt   = (uint4*) (ws + off); off += (size_t)B * C1 * 16;
  u64*    cand    = (u64*)   (ws + off); off += (size_t)B * C1 * SEGS * SEGCAP * 8;
  uint*   cnts    = (uint*)  (ws + off); off += (size_t)B * C1 * SEGS * 4;
  u64*    tkeys   = (u64*)   (ws + off); off += (size_t)B * C1 * KTOP * 8;
  float4* tboxes  = (float4*)(ws + off); off += (size_t)B * C1 * KTOP * 16;
  uint*   tcnt    = (uint*)  (ws + off); off += (size_t)B * C1 * 4;
  u64*    gmaskT  = (u64*)   (ws + off);

  hipMemsetAsync(ghist, 0, (size_t)B * C1 * 256 * 4, stream);

  int perblk = (N + NSPLIT - 1) / NSPLIT;
  prep_kernel<<<B * NSPLIT, NT, 0, stream>>>(
      bboxes, scores, dboxes, conf_th, scale_xy, scale_wh,
      boxesws, lse, keys, ghist, B, N, perblk);

  collect_kernel<<<B * C1 * SEGS, NT, 0, stream>>>(
      keys, ghist, L0cnt, cand, cnts, N);

  topk_kernel<<<B * C1, NT, 0, stream>>>(
      keys, L0cnt, cand, cnts, scores, lse, boxesws, tkeys, tboxes, tcnt, B, N);

  mask_kernel<<<B * C1, NT, 0, stream>>>(tboxes, tcnt, nms_th, gmaskT);

  resolve_kernel<<<B * C1, 64, 0, stream>>>(
      gmaskT, tkeys, tboxes, tcnt, (float*)d_out, B);
}

// Round 9
// 118.255 us; speedup vs baseline: 1.5643x; 1.2057x over previous
//
#include <hip/hip_runtime.h>
#include <math.h>

typedef unsigned int uint;
typedef unsigned short u16;
typedef unsigned long long u64;

#define NT 256
#define KTOP 200
#define CAP 256      // final candidate cap == NT (rank-sort)
#define CAPC 3072    // LDS candidate-list cap
#define SEGS 4       // collect segments per task
#define SEGCAP 512   // per-segment candidate cap in global
#define NCLS 21
#define C1 20
#define MROWS 208
#define NSPLIT 32    // prep blocks per batch image

__device__ __forceinline__ u64 flip64(double d) {
  u64 u = (u64)__double_as_longlong(d);
  return (u & 0x8000000000000000ULL) ? ~u : (u | 0x8000000000000000ULL);
}

__device__ __forceinline__ double unflip64(u64 k) {
  u64 u = (k & 0x8000000000000000ULL) ? (k ^ 0x8000000000000000ULL) : ~k;
  return __longlong_as_double((long long)u);
}

// fast f64 exp for x <= 0: 2^n * exp(r), degree-10 Taylor, rel err ~2e-13
__device__ __forceinline__ double fexp(double x) {
  if (x < -40.0) return 0.0;
  double t = x * 1.4426950408889634074;
  double n = floor(t + 0.5);
  double r = (t - n) * 0.69314718055994530942;
  double y = 2.7557319223985890653e-7;          // 1/10!
  y = y * r + 2.7557319223985890653e-6;         // 1/9!
  y = y * r + 2.4801587301587301587e-5;         // 1/8!
  y = y * r + 1.9841269841269841270e-4;         // 1/7!
  y = y * r + 1.3888888888888888889e-3;         // 1/6!
  y = y * r + 8.3333333333333333333e-3;         // 1/5!
  y = y * r + 4.1666666666666666667e-2;         // 1/4!
  y = y * r + 1.6666666666666666667e-1;         // 1/3!
  y = y * r + 0.5;
  y = y * r + 1.0;
  y = y * r + 1.0;
  int ni = (int)n;
  u64 sb = (u64)(ni + 1023) << 52;
  return y * __longlong_as_double((long long)sb);
}

// monotone u16 fixed-point key for s = log prob; 0 = invalid
__device__ __forceinline__ uint q_key16(float sf) {
  float qf = (sf + 16.0f) * 4096.0f;
  qf = fmaxf(fminf(qf, 65535.0f), 1.0f);
  return (uint)qf;
}

// parallel 256-bin suffix-scan walk: bin = max j with S[j] >= rank.
// res[0]=bin, res[1]=S[bin], res[2]=hist[bin]. All 256 threads must call.
__device__ __forceinline__ void par_walk(const uint* hist, uint* scan, u64* wm,
                                         uint* res, uint rank, int tid) {
  scan[tid] = hist[tid];
  __syncthreads();
#pragma unroll
  for (int off = 1; off < 256; off <<= 1) {
    uint v = scan[tid];
    uint a = (tid + off < 256) ? scan[tid + off] : 0u;
    __syncthreads();
    scan[tid] = v + a;
    __syncthreads();
  }
  u64 m = __ballot(scan[tid] >= rank);
  if ((tid & 63) == 0) wm[tid >> 6] = m;
  __syncthreads();
  if (tid == 0) {
    int bin = 0;
    for (int w = 3; w >= 0; --w) {
      if (wm[w]) { bin = w * 64 + (63 - __clzll(wm[w])); break; }
    }
    res[0] = (uint)bin;
    res[1] = scan[bin];
    res[2] = hist[bin];
  }
  __syncthreads();
}

// ---- K1: decode boxes + f64 LSE + u16 keys + fused 256-bin hist --------------
__global__ __launch_bounds__(NT) void prep_kernel(
    const float* __restrict__ bboxes, const float* __restrict__ scores,
    const float* __restrict__ dboxes, const float* __restrict__ conf_th,
    const float* __restrict__ scale_xy_p, const float* __restrict__ scale_wh_p,
    float4* __restrict__ boxes_out, double* __restrict__ lse_out,
    u16* __restrict__ keys_out, uint* __restrict__ ghist,
    int B, int N, int npad, int perblk)
{
  __shared__ double s_logth[C1];
  __shared__ uint lhist[C1 * 256];
  int tid = threadIdx.x;
  if (tid < C1) s_logth[tid] = log((double)conf_th[tid]);
  for (int i = tid; i < C1 * 256; i += NT) lhist[i] = 0;
  __syncthreads();

  int b = blockIdx.x / NSPLIT, j = blockIdx.x - (blockIdx.x / NSPLIT) * NSPLIT;
  int s0 = j * perblk, e0 = min(N, s0 + perblk);
  float sxy = *scale_xy_p, swh = *scale_wh_p;

  for (int n = s0 + tid; n < e0; n += NT) {
    int gid = b * N + n;
    const float* bb = bboxes + (size_t)b * 4 * N + n;
    float bx = bb[0];
    float by = bb[(size_t)N];
    float bw = bb[2 * (size_t)N];
    float bh = bb[3 * (size_t)N];
    float4 d = reinterpret_cast<const float4*>(dboxes)[n];
    float x = sxy * bx * d.z + d.x;
    float y = sxy * by * d.w + d.y;
    float w = expf(swh * bw) * d.z;
    float h = expf(swh * bh) * d.w;
    boxes_out[gid] = make_float4(x - 0.5f * w, y - 0.5f * h, x + 0.5f * w, y + 0.5f * h);

    const float* sc = scores + (size_t)b * NCLS * N + n;
    float v[NCLS];
    float mx = -INFINITY;
#pragma unroll
    for (int c = 0; c < NCLS; ++c) { v[c] = sc[(size_t)c * N]; mx = fmaxf(mx, v[c]); }
    double sum = 0.0;
#pragma unroll
    for (int c = 0; c < NCLS; ++c) sum += fexp((double)(v[c] - mx));
    double lse = (double)mx + log(sum);
    lse_out[gid] = lse;

#pragma unroll
    for (int c = 0; c < C1; ++c) {
      double s = (double)v[c + 1] - lse;
      uint key = 0;
      if (s > s_logth[c]) key = q_key16((float)s);
      keys_out[((size_t)b * C1 + c) * npad + n] = (u16)key;
      if (key) atomicAdd(&lhist[c * 256 + (key >> 8)], 1u);
    }
  }
  // zero key padding (last slice only)
  if (j == NSPLIT - 1 && npad > N) {
    int pad = npad - N;
    for (int t = tid; t < pad * C1; t += NT) {
      int c = t / pad, n = N + (t - c * pad);
      keys_out[((size_t)b * C1 + c) * npad + n] = 0;
    }
  }
  __syncthreads();
  for (int i = tid; i < C1 * 256; i += NT) {
    uint v = lhist[i];
    if (v) atomicAdd(&ghist[((size_t)b * C1 + (i >> 8)) * 256 + (i & 255)], v);
  }
}

// ---- K2: inline walk + distributed collect (B*C1*SEGS blocks, u16 keys) ------
__global__ __launch_bounds__(NT) void collect_kernel(
    const u16* __restrict__ keys, const uint* __restrict__ ghist,
    uint4* __restrict__ L0cnt, uint* __restrict__ cand, uint* __restrict__ cnts,
    int npad)
{
  int blk = blockIdx.x;
  int task = blk >> 2, seg = blk & (SEGS - 1);
  int tid = threadIdx.x, lane = tid & 63;
  __shared__ uint sL, sCnt0, sCnt;

  if (tid < 64) {
    uint4 h = reinterpret_cast<const uint4*>(ghist + (size_t)task * 256)[tid];
    uint s = h.x + h.y + h.z + h.w;
    uint suf = s;
#pragma unroll
    for (int off = 1; off < 64; off <<= 1) {
      uint o = (uint)__shfl_down((int)suf, off);
      if (lane + off < 64) suf += o;
    }
    uint total = (uint)__shfl((int)suf, 0);
    uint sn = (uint)__shfl_down((int)suf, 1);
    if (lane == 63) sn = 0;
    uint c3 = h.w + sn, c2 = c3 + h.z, c1 = c2 + h.y, c0 = c1 + h.x;
    uint binoff, cnt, abv;
    if (c3 >= KTOP)      { binoff = 3; cnt = c3; abv = c3 - h.w; }
    else if (c2 >= KTOP) { binoff = 2; cnt = c2; abv = c2 - h.z; }
    else if (c1 >= KTOP) { binoff = 1; cnt = c1; abv = c1 - h.y; }
    else                 { binoff = 0; cnt = c0; abv = c0 - h.x; }
    uint L0v, cnt0v, abovev;
    if (total < KTOP) {
      L0v = 1u; cnt0v = total; abovev = 0u;
    } else {
      u64 m = __ballot(suf >= KTOP);
      int l = 63 - __clzll(m);
      uint bo = (uint)__shfl((int)binoff, l);
      cnt0v = (uint)__shfl((int)cnt, l);
      abovev = (uint)__shfl((int)abv, l);
      L0v = ((uint)(4 * l) + bo) << 8;
    }
    if (lane == 0) {
      sL = L0v; sCnt0 = cnt0v;
      if (seg == 0) L0cnt[task] = make_uint4(L0v, cnt0v, abovev, total);
    }
  }
  if (tid == NT - 1) sCnt = 0;
  __syncthreads();

  uint L = sL, cnt0 = sCnt0;
  if (cnt0 > CAPC) { if (tid == 0) cnts[blk] = 0; return; }   // slow path in K3

  const u16* krow = keys + (size_t)task * npad;
  const uint4* krow8 = reinterpret_cast<const uint4*>(krow);
  int nv8 = npad >> 3;
  int per8 = (nv8 + SEGS - 1) >> 2;
  int s8 = seg * per8, e8 = min(nv8, s8 + per8);
  uint* myc = cand + ((size_t)task * SEGS + seg) * SEGCAP;

  for (int i = s8 + tid; i < e8; i += NT) {
    uint4 kv = krow8[i];
    uint base = (uint)(i << 3);
    uint ks[8] = { kv.x & 0xFFFFu, kv.x >> 16, kv.y & 0xFFFFu, kv.y >> 16,
                   kv.z & 0xFFFFu, kv.z >> 16, kv.w & 0xFFFFu, kv.w >> 16 };
#pragma unroll
    for (int comp = 0; comp < 8; ++comp) {
      uint k = ks[comp];
      bool f = (k >= L);
      u64 m = __ballot(f);
      if (m) {
        uint nb = (uint)__popcll(m);
        uint wb = 0;
        if (lane == 0) wb = atomicAdd(&sCnt, nb);
        wb = (uint)__shfl((int)wb, 0);
        if (f) {
          uint pos = wb + (uint)__popcll(m & ((1ULL << lane) - 1ULL));
          if (pos < SEGCAP) myc[pos] = (k << 15) | (base + comp);
        }
      }
    }
  }
  __syncthreads();
  if (tid == 0) cnts[blk] = sCnt;      // actual (uncapped) count
}

// ---- K3: narrow -> rank-sort -> register-blocked mask -> resolve -> output ---
__global__ __launch_bounds__(NT) void final_kernel(
    const u16* __restrict__ keys, const uint4* __restrict__ L0cnt,
    const uint* __restrict__ candg, const uint* __restrict__ cnts,
    const float* __restrict__ scores, const double* __restrict__ lse,
    const float4* __restrict__ boxesws, const float* __restrict__ nms_th_p,
    float* __restrict__ out, int B, int N, int npad)
{
  int task = blockIdx.x;
  int b = task / C1, c = task - b * C1;
  int tid = threadIdx.x, lane = tid & 63, wav = tid >> 6;
  const u16* krow = keys + (size_t)task * npad;
  int nv8 = npad >> 3;

  __shared__ uint cand[CAPC];            // 12 KB
  __shared__ uint histB[256];
  __shared__ uint scanB[256];
  __shared__ u64 wmB[4];
  __shared__ uint res3[4];
  __shared__ uint scq[SEGS];
  __shared__ int si[CAP];
  __shared__ u64 skey[CAP];
  __shared__ u64 skid[CAP];
  __shared__ float4 sbox[MROWS];
  __shared__ float sar[MROWS];
  __shared__ u64 smaskT[13][64];
  __shared__ u64 saliveW[4];
  __shared__ uint sCnt, sCnt2;

  uint4 w0 = L0cnt[task];
  uint cnt0 = w0.y;
  if (tid < SEGS) scq[tid] = cnts[task * SEGS + tid];
  if (tid == 0) { sCnt = 0; sCnt2 = 0; }
  // zero-fill box arrays (scatter only writes r < valid)
  if (tid < MROWS) { sbox[tid] = make_float4(0.f, 0.f, 0.f, 0.f); sar[tid] = 0.f; }
  __syncthreads();
  bool slow = (cnt0 > CAPC) ||
              (scq[0] > SEGCAP) || (scq[1] > SEGCAP) ||
              (scq[2] > SEGCAP) || (scq[3] > SEGCAP);

  uint pref = w0.x >> 8, above = w0.z, rank = KTOP - w0.z;
  uint cnt;

  if (!slow) {
    uint off1 = scq[0], off2 = off1 + scq[1], off3 = off2 + scq[2];
    cnt = off3 + scq[3];
    const uint* cg = candg + (size_t)task * SEGS * SEGCAP;
    for (int j = tid; j < (int)scq[0]; j += NT) cand[j] = cg[j];
    for (int j = tid; j < (int)scq[1]; j += NT) cand[off1 + j] = cg[SEGCAP + j];
    for (int j = tid; j < (int)scq[2]; j += NT) cand[off2 + j] = cg[2 * SEGCAP + j];
    for (int j = tid; j < (int)scq[3]; j += NT) cand[off3 + j] = cg[3 * SEGCAP + j];
    __syncthreads();
  } else {
    // rare: refine exact u16 threshold over full row, then collect
    const uint4* krow8 = reinterpret_cast<const uint4*>(krow);
    histB[tid] = 0;
    __syncthreads();
    for (int i = tid; i < nv8; i += NT) {
      uint4 kv = krow8[i];
      uint ks[8] = { kv.x & 0xFFFFu, kv.x >> 16, kv.y & 0xFFFFu, kv.y >> 16,
                     kv.z & 0xFFFFu, kv.z >> 16, kv.w & 0xFFFFu, kv.w >> 16 };
#pragma unroll
      for (int comp = 0; comp < 8; ++comp) {
        uint k = ks[comp];
        if ((k >> 8) == pref) atomicAdd(&histB[k & 255u], 1u);
      }
    }
    __syncthreads();
    par_walk(histB, scanB, wmB, res3, rank, tid);
    uint Ts = (pref << 8) | res3[0];
    for (int i = tid; i < nv8; i += NT) {
      uint4 kv = krow8[i];
      uint base = (uint)(i << 3);
      uint ks[8] = { kv.x & 0xFFFFu, kv.x >> 16, kv.y & 0xFFFFu, kv.y >> 16,
                     kv.z & 0xFFFFu, kv.z >> 16, kv.w & 0xFFFFu, kv.w >> 16 };
#pragma unroll
      for (int comp = 0; comp < 8; ++comp) {
        uint k = ks[comp];
        bool f = (k >= Ts);
        u64 m = __ballot(f);
        if (m) {
          uint nb = (uint)__popcll(m);
          uint wb = 0;
          if (lane == 0) wb = atomicAdd(&sCnt, nb);
          wb = (uint)__shfl((int)wb, 0);
          if (f) {
            uint pos = wb + (uint)__popcll(m & ((1ULL << lane) - 1ULL));
            if (pos < CAPC) cand[pos] = (k << 15) | (base + comp);
          }
        }
      }
    }
    __syncthreads();
    cnt = min(sCnt, (uint)CAPC);
  }

  // ---------- narrow candidate list to <= CAP (one 256-bin level, exact key)
  uint cntF;
  if (cnt <= CAP) {
    for (int p = tid; p < (int)cnt; p += NT) si[p] = (int)(cand[p] & 0x7FFFu);
    __syncthreads();
    cntF = cnt;
  } else {
    histB[tid] = 0;
    __syncthreads();
    for (int p = tid; p < (int)cnt; p += NT) {
      uint k = cand[p] >> 15;
      if ((k >> 8) == pref) atomicAdd(&histB[k & 255u], 1u);
    }
    __syncthreads();
    par_walk(histB, scanB, wmB, res3, rank, tid);
    uint T = (pref << 8) | res3[0];
    for (int p = tid; p < (int)cnt; p += NT) {
      uint cd = cand[p];
      if ((cd >> 15) >= T) {
        uint q = atomicAdd(&sCnt2, 1u);
        if (q < CAP) si[q] = (int)(cd & 0x7FFFu);
      }
    }
    __syncthreads();
    cntF = min(sCnt2, (uint)CAP);
  }

  int valid_cnt = (int)min(cntF, (uint)KTOP);

  // ---------- gather exact f64 scores; pad; rank-sort; scatter sorted boxes
  {
    int p = tid;
    if (p < (int)cntF) {
      int n = si[p];
      double s = (double)scores[((size_t)b * NCLS + (c + 1)) * N + n] - lse[(size_t)b * N + n];
      skey[p] = flip64(s);
    } else {
      skey[p] = 0ULL;
      si[p] = 0x40000000 + p;
    }
  }
  __syncthreads();
  {
    u64 kp = skey[tid];
    int ip = si[tid];
    int r = 0;
#pragma unroll 4
    for (int jj = 0; jj < CAP; ++jj) {
      u64 kj = skey[jj];
      int ij = si[jj];
      r += ((kj > kp) || (kj == kp && ij < ip)) ? 1 : 0;
    }
    skid[r] = kp;
    if (tid < (int)cntF && r < KTOP) {
      float4 bx = boxesws[(size_t)b * N + ip];
      sbox[r] = bx;
      sar[r] = fmaxf(bx.z - bx.x, 0.f) * fmaxf(bx.w - bx.y, 0.f);
    }
  }
  __syncthreads();

  float nth = *nms_th_p;

  // ---------- register-blocked suppression mask, transposed-native
  // lane owns boxes j = lane + 64k (k<4) in registers; per row: broadcast read
  {
    float4 jb0 = sbox[lane], jb1 = sbox[lane + 64],
           jb2 = sbox[lane + 128], jb3 = sbox[lane + 192 < MROWS ? lane + 192 : 0];
    if (lane + 192 >= MROWS) jb3 = make_float4(0.f, 0.f, 0.f, 0.f);
    float ja0 = sar[lane], ja1 = sar[lane + 64], ja2 = sar[lane + 128],
          ja3 = (lane + 192 < MROWS) ? sar[lane + 192] : 0.f;
    for (int w = wav; w < 13; w += 4) {
      u64 word = 0;
      int r0 = w * 16;
#pragma unroll
      for (int rr = 0; rr < 16; ++rr) {
        int r = r0 + rr;
        float4 rb = sbox[r];
        float ra = sar[r];
        uint nib = 0;
#define IOU_BIT(K, JB, JA) { \
        int j = lane + 64 * (K); \
        float xx1 = fmaxf(rb.x, JB.x), yy1 = fmaxf(rb.y, JB.y); \
        float xx2 = fminf(rb.z, JB.z), yy2 = fminf(rb.w, JB.w); \
        float ww = fmaxf(xx2 - xx1, 0.f), hh = fmaxf(yy2 - yy1, 0.f); \
        float inter = ww * hh; \
        float den = ((ra + JA) - inter) + 1e-9f; \
        if ((inter >= nth * den) && (j > r)) nib |= 1u << (K); }
        IOU_BIT(0, jb0, ja0) IOU_BIT(1, jb1, ja1)
        IOU_BIT(2, jb2, ja2) IOU_BIT(3, jb3, ja3)
#undef IOU_BIT
        word |= (u64)nib << (rr * 4);
      }
      smaskT[w][lane] = word;
    }
  }
  __syncthreads();

  // ---------- greedy resolve: wave 0, masks in registers, in-lane unrolled
  if (tid < 64) {
    u64 mm[13];
#pragma unroll
    for (int w = 0; w < 13; ++w) mm[w] = smaskT[w][lane];
    uint av = 0;
#pragma unroll
    for (int k = 0; k < 4; ++k)
      if (lane + 64 * k < valid_cnt) av |= 1u << k;
#define STEP(i) { \
    u64 bm = __ballot((lane == ((i) & 63)) && ((av >> ((i) >> 6)) & 1u)); \
    if (bm) av &= ~((uint)((mm[(i) >> 4] >> (((i) & 15) * 4)) & 0xFULL)); }
#define S4(i)  STEP(i) STEP((i)+1) STEP((i)+2) STEP((i)+3)
#define S16(i) S4(i) S4((i)+4) S4((i)+8) S4((i)+12)
#define S64(i) S16(i) S16((i)+16) S16((i)+32) S16((i)+48)
    S64(0) S64(64) S64(128) S16(192)
#undef S64
#undef S16
#undef S4
#undef STEP
#pragma unroll
    for (int k = 0; k < 4; ++k) {
      u64 bb = __ballot((av >> k) & 1u);
      if (lane == 0) saliveW[k] = bb;
    }
  }
  __syncthreads();

  // ---------- outputs: boxes | labels | scores | keep
  size_t M = (size_t)C1 * KTOP;
  float* out_boxes  = out;
  float* out_labels = out + (size_t)B * M * 4;
  float* out_scores = out_labels + (size_t)B * M;
  float* out_keep   = out_scores + (size_t)B * M;
  if (tid < KTOP) {
    size_t slot = ((size_t)b * C1 + c) * KTOP + tid;
    bool kept = (tid < valid_cnt) && ((saliveW[tid >> 6] >> (tid & 63)) & 1ULL);
    float4 bx = kept ? sbox[tid] : make_float4(0.f, 0.f, 0.f, 0.f);
    reinterpret_cast<float4*>(out_boxes)[slot] = bx;
    out_labels[slot] = kept ? (float)(c + 1) : 0.0f;
    out_scores[slot] = kept ? (float)exp(unflip64(skid[tid])) : 0.0f;
    out_keep[slot]   = kept ? 1.0f : 0.0f;
  }
}

extern "C" void kernel_launch(void* const* d_in, const int* in_sizes, int n_in,
                              void* d_out, int out_size, void* d_ws, size_t ws_size,
                              hipStream_t stream) {
  const float* bboxes   = (const float*)d_in[0];   // [B,4,N]
  const float* scores   = (const float*)d_in[1];   // [B,21,N]
  const float* dboxes   = (const float*)d_in[2];   // [1,N,4]
  const float* conf_th  = (const float*)d_in[3];   // [20]
  const float* nms_th   = (const float*)d_in[4];   // scalar
  const float* scale_xy = (const float*)d_in[6];   // scalar
  const float* scale_wh = (const float*)d_in[7];   // scalar

  int N = in_sizes[2] / 4;
  int B = in_sizes[0] / (4 * N);
  int npad = (N + 7) & ~7;

  // ws: lse | boxes | keys(u16) | ghist | L0cnt | cand(u32) | cnts
  char* ws = (char*)d_ws;
  size_t off = 0;
  double* lse     = (double*)(ws + off); off += (size_t)B * N * 8;
  float4* boxesws = (float4*)(ws + off); off += (size_t)B * N * 16;
  u16*    keys    = (u16*)   (ws + off); off += (size_t)B * C1 * npad * 2;
  uint*   ghist   = (uint*)  (ws + off); off += (size_t)B * C1 * 256 * 4;
  uint4*  L0cnt   = (uint4*) (ws + off); off += (size_t)B * C1 * 16;
  uint*   cand    = (uint*)  (ws + off); off += (size_t)B * C1 * SEGS * SEGCAP * 4;
  uint*   cnts    = (uint*)  (ws + off);

  hipMemsetAsync(ghist, 0, (size_t)B * C1 * 256 * 4, stream);

  int perblk = (N + NSPLIT - 1) / NSPLIT;
  prep_kernel<<<B * NSPLIT, NT, 0, stream>>>(
      bboxes, scores, dboxes, conf_th, scale_xy, scale_wh,
      boxesws, lse, keys, ghist, B, N, npad, perblk);

  collect_kernel<<<B * C1 * SEGS, NT, 0, stream>>>(
      keys, ghist, L0cnt, cand, cnts, npad);

  final_kernel<<<B * C1, NT, 0, stream>>>(
      keys, L0cnt, cand, cnts, scores, lse, boxesws, nms_th,
      (float*)d_out, B, N, npad);
}

// Round 10
// 105.734 us; speedup vs baseline: 1.7496x; 1.1184x over previous
//
#include <hip/hip_runtime.h>
#include <math.h>

typedef unsigned int uint;
typedef unsigned short u16;
typedef unsigned long long u64;

#define NT 256
#define KTOP 200
#define CAP 256      // final candidate cap == NT (rank-sort)
#define CAPC 3072    // LDS candidate-list cap
#define SEGS 4       // collect segments per task
#define SEGCAP 512   // per-segment candidate cap in global
#define NCLS 21
#define C1 20
#define MROWS 208
#define NSPLIT 48    // prep blocks per batch image

__device__ __forceinline__ u64 flip64(double d) {
  u64 u = (u64)__double_as_longlong(d);
  return (u & 0x8000000000000000ULL) ? ~u : (u | 0x8000000000000000ULL);
}

__device__ __forceinline__ double unflip64(u64 k) {
  u64 u = (k & 0x8000000000000000ULL) ? (k ^ 0x8000000000000000ULL) : ~k;
  return __longlong_as_double((long long)u);
}

// fast f64 exp for x <= 0: 2^n * exp(r), degree-10 Taylor, rel err ~2e-13
__device__ __forceinline__ double fexp(double x) {
  if (x < -40.0) return 0.0;
  double t = x * 1.4426950408889634074;
  double n = floor(t + 0.5);
  double r = (t - n) * 0.69314718055994530942;
  double y = 2.7557319223985890653e-7;
  y = y * r + 2.7557319223985890653e-6;
  y = y * r + 2.4801587301587301587e-5;
  y = y * r + 1.9841269841269841270e-4;
  y = y * r + 1.3888888888888888889e-3;
  y = y * r + 8.3333333333333333333e-3;
  y = y * r + 4.1666666666666666667e-2;
  y = y * r + 1.6666666666666666667e-1;
  y = y * r + 0.5;
  y = y * r + 1.0;
  y = y * r + 1.0;
  int ni = (int)n;
  u64 sb = (u64)(ni + 1023) << 52;
  return y * __longlong_as_double((long long)sb);
}

// monotone u16 fixed-point key for s = log prob; 0 = invalid
__device__ __forceinline__ uint q_key16(float sf) {
  float qf = (sf + 16.0f) * 4096.0f;
  qf = fmaxf(fminf(qf, 65535.0f), 1.0f);
  return (uint)qf;
}

// parallel 256-bin suffix-scan walk: bin = max j with S[j] >= rank.
__device__ __forceinline__ void par_walk(const uint* hist, uint* scan, u64* wm,
                                         uint* res, uint rank, int tid) {
  scan[tid] = hist[tid];
  __syncthreads();
#pragma unroll
  for (int off = 1; off < 256; off <<= 1) {
    uint v = scan[tid];
    uint a = (tid + off < 256) ? scan[tid + off] : 0u;
    __syncthreads();
    scan[tid] = v + a;
    __syncthreads();
  }
  u64 m = __ballot(scan[tid] >= rank);
  if ((tid & 63) == 0) wm[tid >> 6] = m;
  __syncthreads();
  if (tid == 0) {
    int bin = 0;
    for (int w = 3; w >= 0; --w) {
      if (wm[w]) { bin = w * 64 + (63 - __clzll(wm[w])); break; }
    }
    res[0] = (uint)bin;
    res[1] = scan[bin];
    res[2] = hist[bin];
  }
  __syncthreads();
}

// ---- K1: decode boxes + f64 LSE + u16 keys + fused 256-bin hist --------------
__global__ __launch_bounds__(NT) void prep_kernel(
    const float* __restrict__ bboxes, const float* __restrict__ scores,
    const float* __restrict__ dboxes, const float* __restrict__ conf_th,
    const float* __restrict__ scale_xy_p, const float* __restrict__ scale_wh_p,
    float4* __restrict__ boxes_out, double* __restrict__ lse_out,
    u16* __restrict__ keys_out, uint* __restrict__ ghist,
    int B, int N, int npad, int perblk)
{
  __shared__ double s_logth[C1];
  __shared__ uint lhist[C1 * 256];
  int tid = threadIdx.x;
  if (tid < C1) s_logth[tid] = log((double)conf_th[tid]);
  for (int i = tid; i < C1 * 256; i += NT) lhist[i] = 0;
  __syncthreads();

  int b = blockIdx.x / NSPLIT, j = blockIdx.x - b * NSPLIT;
  int s0 = j * perblk, e0 = min(N, s0 + perblk);
  float sxy = *scale_xy_p, swh = *scale_wh_p;

  for (int n = s0 + tid; n < e0; n += NT) {
    int gid = b * N + n;
    const float* bb = bboxes + (size_t)b * 4 * N + n;
    float bx = bb[0];
    float by = bb[(size_t)N];
    float bw = bb[2 * (size_t)N];
    float bh = bb[3 * (size_t)N];
    float4 d = reinterpret_cast<const float4*>(dboxes)[n];
    float x = sxy * bx * d.z + d.x;
    float y = sxy * by * d.w + d.y;
    float w = expf(swh * bw) * d.z;
    float h = expf(swh * bh) * d.w;
    boxes_out[gid] = make_float4(x - 0.5f * w, y - 0.5f * h, x + 0.5f * w, y + 0.5f * h);

    const float* sc = scores + (size_t)b * NCLS * N + n;
    float v[NCLS];
    float mx = -INFINITY;
#pragma unroll
    for (int c = 0; c < NCLS; ++c) { v[c] = sc[(size_t)c * N]; mx = fmaxf(mx, v[c]); }
    double sum = 0.0;
#pragma unroll
    for (int c = 0; c < NCLS; ++c) sum += fexp((double)(v[c] - mx));
    double lse = (double)mx + log(sum);
    lse_out[gid] = lse;

#pragma unroll
    for (int c = 0; c < C1; ++c) {
      double s = (double)v[c + 1] - lse;
      uint key = 0;
      if (s > s_logth[c]) key = q_key16((float)s);
      keys_out[((size_t)b * C1 + c) * npad + n] = (u16)key;
      if (key) atomicAdd(&lhist[c * 256 + (key >> 8)], 1u);
    }
  }
  if (j == NSPLIT - 1 && npad > N) {
    int pad = npad - N;
    for (int t = tid; t < pad * C1; t += NT) {
      int c = t / pad, n = N + (t - c * pad);
      keys_out[((size_t)b * C1 + c) * npad + n] = 0;
    }
  }
  __syncthreads();
  for (int i = tid; i < C1 * 256; i += NT) {
    uint v = lhist[i];
    if (v) atomicAdd(&ghist[((size_t)b * C1 + (i >> 8)) * 256 + (i & 255)], v);
  }
}

// ---- K2: inline walk + distributed collect (B*C1*SEGS blocks, u16 keys) ------
__global__ __launch_bounds__(NT) void collect_kernel(
    const u16* __restrict__ keys, const uint* __restrict__ ghist,
    uint4* __restrict__ L0cnt, uint* __restrict__ cand, uint* __restrict__ cnts,
    int npad)
{
  int blk = blockIdx.x;
  int task = blk >> 2, seg = blk & (SEGS - 1);
  int tid = threadIdx.x, lane = tid & 63;
  __shared__ uint sL, sCnt0, sCnt;

  if (tid < 64) {
    uint4 h = reinterpret_cast<const uint4*>(ghist + (size_t)task * 256)[tid];
    uint s = h.x + h.y + h.z + h.w;
    uint suf = s;
#pragma unroll
    for (int off = 1; off < 64; off <<= 1) {
      uint o = (uint)__shfl_down((int)suf, off);
      if (lane + off < 64) suf += o;
    }
    uint total = (uint)__shfl((int)suf, 0);
    uint sn = (uint)__shfl_down((int)suf, 1);
    if (lane == 63) sn = 0;
    uint c3 = h.w + sn, c2 = c3 + h.z, c1 = c2 + h.y, c0 = c1 + h.x;
    uint binoff, cnt, abv;
    if (c3 >= KTOP)      { binoff = 3; cnt = c3; abv = c3 - h.w; }
    else if (c2 >= KTOP) { binoff = 2; cnt = c2; abv = c2 - h.z; }
    else if (c1 >= KTOP) { binoff = 1; cnt = c1; abv = c1 - h.y; }
    else                 { binoff = 0; cnt = c0; abv = c0 - h.x; }
    uint L0v, cnt0v, abovev;
    if (total < KTOP) {
      L0v = 1u; cnt0v = total; abovev = 0u;
    } else {
      u64 m = __ballot(suf >= KTOP);
      int l = 63 - __clzll(m);
      uint bo = (uint)__shfl((int)binoff, l);
      cnt0v = (uint)__shfl((int)cnt, l);
      abovev = (uint)__shfl((int)abv, l);
      L0v = ((uint)(4 * l) + bo) << 8;
    }
    if (lane == 0) {
      sL = L0v; sCnt0 = cnt0v;
      if (seg == 0) L0cnt[task] = make_uint4(L0v, cnt0v, abovev, total);
    }
  }
  if (tid == NT - 1) sCnt = 0;
  __syncthreads();

  uint L = sL, cnt0 = sCnt0;
  if (cnt0 > CAPC) { if (tid == 0) cnts[blk] = 0; return; }   // slow path in F1

  const u16* krow = keys + (size_t)task * npad;
  const uint4* krow8 = reinterpret_cast<const uint4*>(krow);
  int nv8 = npad >> 3;
  int per8 = (nv8 + SEGS - 1) >> 2;
  int s8 = seg * per8, e8 = min(nv8, s8 + per8);
  uint* myc = cand + ((size_t)task * SEGS + seg) * SEGCAP;

  for (int i = s8 + tid; i < e8; i += NT) {
    uint4 kv = krow8[i];
    uint base = (uint)(i << 3);
    uint ks[8] = { kv.x & 0xFFFFu, kv.x >> 16, kv.y & 0xFFFFu, kv.y >> 16,
                   kv.z & 0xFFFFu, kv.z >> 16, kv.w & 0xFFFFu, kv.w >> 16 };
#pragma unroll
    for (int comp = 0; comp < 8; ++comp) {
      uint k = ks[comp];
      bool f = (k >= L);
      u64 m = __ballot(f);
      if (m) {
        uint nb = (uint)__popcll(m);
        uint wb = 0;
        if (lane == 0) wb = atomicAdd(&sCnt, nb);
        wb = (uint)__shfl((int)wb, 0);
        if (f) {
          uint pos = wb + (uint)__popcll(m & ((1ULL << lane) - 1ULL));
          if (pos < SEGCAP) myc[pos] = (k << 15) | (base + comp);
        }
      }
    }
  }
  __syncthreads();
  if (tid == 0) cnts[blk] = sCnt;      // actual (uncapped) count
}

// ---- F1: narrow -> gather (+box prefetch) -> rank-sort -> write top-K --------
__global__ __launch_bounds__(NT) void topk_kernel(
    const u16* __restrict__ keys, const uint4* __restrict__ L0cnt,
    const uint* __restrict__ candg, const uint* __restrict__ cnts,
    const float* __restrict__ scores, const double* __restrict__ lse,
    const float4* __restrict__ boxesws,
    u64* __restrict__ tkeys, float4* __restrict__ tbox, uint* __restrict__ tcnt,
    int B, int N, int npad)
{
  int task = blockIdx.x;
  int b = task / C1, c = task - b * C1;
  int tid = threadIdx.x, lane = tid & 63;
  const u16* krow = keys + (size_t)task * npad;
  int nv8 = npad >> 3;

  __shared__ uint cand[CAPC];            // 12 KB
  __shared__ uint histB[256];
  __shared__ uint scanB[256];
  __shared__ u64 wmB[4];
  __shared__ uint res3[4];
  __shared__ uint scq[SEGS];
  __shared__ int si[CAP];
  __shared__ u64 sC[CAP];
  __shared__ float4 sbx[CAP];
  __shared__ uint sCnt, sCnt2;

  uint4 w0 = L0cnt[task];
  uint cnt0 = w0.y;
  if (tid < SEGS) scq[tid] = cnts[task * SEGS + tid];
  if (tid == 0) { sCnt = 0; sCnt2 = 0; }
  __syncthreads();
  bool slow = (cnt0 > CAPC) ||
              (scq[0] > SEGCAP) || (scq[1] > SEGCAP) ||
              (scq[2] > SEGCAP) || (scq[3] > SEGCAP);

  uint pref = w0.x >> 8, above = w0.z, rank = KTOP - w0.z;
  uint cnt;

  if (!slow) {
    uint off1 = scq[0], off2 = off1 + scq[1], off3 = off2 + scq[2];
    cnt = off3 + scq[3];
    const uint* cg = candg + (size_t)task * SEGS * SEGCAP;
    for (int j = tid; j < (int)scq[0]; j += NT) cand[j] = cg[j];
    for (int j = tid; j < (int)scq[1]; j += NT) cand[off1 + j] = cg[SEGCAP + j];
    for (int j = tid; j < (int)scq[2]; j += NT) cand[off2 + j] = cg[2 * SEGCAP + j];
    for (int j = tid; j < (int)scq[3]; j += NT) cand[off3 + j] = cg[3 * SEGCAP + j];
    __syncthreads();
  } else {
    const uint4* krow8 = reinterpret_cast<const uint4*>(krow);
    histB[tid] = 0;
    __syncthreads();
    for (int i = tid; i < nv8; i += NT) {
      uint4 kv = krow8[i];
      uint ks[8] = { kv.x & 0xFFFFu, kv.x >> 16, kv.y & 0xFFFFu, kv.y >> 16,
                     kv.z & 0xFFFFu, kv.z >> 16, kv.w & 0xFFFFu, kv.w >> 16 };
#pragma unroll
      for (int comp = 0; comp < 8; ++comp) {
        uint k = ks[comp];
        if ((k >> 8) == pref) atomicAdd(&histB[k & 255u], 1u);
      }
    }
    __syncthreads();
    par_walk(histB, scanB, wmB, res3, rank, tid);
    uint Ts = (pref << 8) | res3[0];
    for (int i = tid; i < nv8; i += NT) {
      uint4 kv = krow8[i];
      uint base = (uint)(i << 3);
      uint ks[8] = { kv.x & 0xFFFFu, kv.x >> 16, kv.y & 0xFFFFu, kv.y >> 16,
                     kv.z & 0xFFFFu, kv.z >> 16, kv.w & 0xFFFFu, kv.w >> 16 };
#pragma unroll
      for (int comp = 0; comp < 8; ++comp) {
        uint k = ks[comp];
        bool f = (k >= Ts);
        u64 m = __ballot(f);
        if (m) {
          uint nb = (uint)__popcll(m);
          uint wb = 0;
          if (lane == 0) wb = atomicAdd(&sCnt, nb);
          wb = (uint)__shfl((int)wb, 0);
          if (f) {
            uint pos = wb + (uint)__popcll(m & ((1ULL << lane) - 1ULL));
            if (pos < CAPC) cand[pos] = (k << 15) | (base + comp);
          }
        }
      }
    }
    __syncthreads();
    cnt = min(sCnt, (uint)CAPC);
  }

  // ---------- narrow candidate list to <= CAP (one 256-bin level, exact key)
  uint cntF;
  if (cnt <= CAP) {
    for (int p = tid; p < (int)cnt; p += NT) si[p] = (int)(cand[p] & 0x7FFFu);
    __syncthreads();
    cntF = cnt;
  } else {
    histB[tid] = 0;
    __syncthreads();
    for (int p = tid; p < (int)cnt; p += NT) {
      uint k = cand[p] >> 15;
      if ((k >> 8) == pref) atomicAdd(&histB[k & 255u], 1u);
    }
    __syncthreads();
    par_walk(histB, scanB, wmB, res3, rank, tid);
    uint T = (pref << 8) | res3[0];
    for (int p = tid; p < (int)cnt; p += NT) {
      uint cd = cand[p];
      if ((cd >> 15) >= T) {
        uint q = atomicAdd(&sCnt2, 1u);
        if (q < CAP) si[q] = (int)(cd & 0x7FFFu);
      }
    }
    __syncthreads();
    cntF = min(sCnt2, (uint)CAP);
  }

  // ---------- gather f64 score + box; composite key with idx tiebreak in低15
  {
    int p = tid;
    u64 C;
    if (p < (int)cntF) {
      int n = si[p];
      double s = (double)scores[((size_t)b * NCLS + (c + 1)) * N + n] - lse[(size_t)b * N + n];
      u64 f = flip64(s);
      C = (f & ~0x7FFFULL) | (u64)(32767 - n);
      sbx[p] = boxesws[(size_t)b * N + n];
    } else {
      C = (u64)p;   // pads sort below all valid keys (valid flipped keys ~4.6e18)
      sbx[p] = make_float4(0.f, 0.f, 0.f, 0.f);
    }
    sC[p] = C;
  }
  __syncthreads();

  // ---------- rank-sort: single u64 compare (keys all distinct)
  {
    u64 kp = sC[tid];
    int r = 0;
#pragma unroll 8
    for (int jj = 0; jj < CAP; ++jj) r += (sC[jj] > kp) ? 1 : 0;
    if (r < KTOP) {
      tkeys[(size_t)task * KTOP + r] = kp;
      tbox[(size_t)task * KTOP + r] = sbx[tid];
    }
  }
  if (tid == 0) tcnt[task] = min(cntF, (uint)KTOP);
}

// ---- F2: register-blocked mask + 1-wave resolve + output --------------------
__global__ __launch_bounds__(NT) void maskresolve_kernel(
    const u64* __restrict__ tkeys, const float4* __restrict__ tbox,
    const uint* __restrict__ tcnt, const float* __restrict__ nms_th_p,
    float* __restrict__ out, int B)
{
  int task = blockIdx.x;
  int b = task / C1, c = task - b * C1;
  int tid = threadIdx.x, lane = tid & 63, wav = tid >> 6;

  __shared__ float4 sbox[MROWS];
  __shared__ float sar[MROWS];
  __shared__ u64 smaskT[13][64];
  __shared__ u64 saliveW[4];

  int valid = (int)tcnt[task];
  float nth = *nms_th_p;

  if (tid < MROWS) {
    float4 bx = (tid < valid) ? tbox[(size_t)task * KTOP + tid]
                              : make_float4(0.f, 0.f, 0.f, 0.f);
    sbox[tid] = bx;
    sar[tid] = fmaxf(bx.z - bx.x, 0.f) * fmaxf(bx.w - bx.y, 0.f);
  }
  __syncthreads();

  {
    float4 jb0 = sbox[lane], jb1 = sbox[lane + 64], jb2 = sbox[lane + 128];
    float4 jb3 = (lane + 192 < MROWS) ? sbox[lane + 192]
                                      : make_float4(0.f, 0.f, 0.f, 0.f);
    float ja0 = sar[lane], ja1 = sar[lane + 64], ja2 = sar[lane + 128],
          ja3 = (lane + 192 < MROWS) ? sar[lane + 192] : 0.f;
    for (int w = wav; w < 13; w += 4) {
      u64 word = 0;
      int r0 = w * 16;
#pragma unroll
      for (int rr = 0; rr < 16; ++rr) {
        int r = r0 + rr;
        float4 rb = sbox[r];
        float ra = sar[r];
        uint nib = 0;
#define IOU_BIT(K, JB, JA) { \
        int j = lane + 64 * (K); \
        float xx1 = fmaxf(rb.x, JB.x), yy1 = fmaxf(rb.y, JB.y); \
        float xx2 = fminf(rb.z, JB.z), yy2 = fminf(rb.w, JB.w); \
        float ww = fmaxf(xx2 - xx1, 0.f), hh = fmaxf(yy2 - yy1, 0.f); \
        float inter = ww * hh; \
        float den = ((ra + JA) - inter) + 1e-9f; \
        if ((inter >= nth * den) && (j > r)) nib |= 1u << (K); }
        IOU_BIT(0, jb0, ja0) IOU_BIT(1, jb1, ja1)
        IOU_BIT(2, jb2, ja2) IOU_BIT(3, jb3, ja3)
#undef IOU_BIT
        word |= (u64)nib << (rr * 4);
      }
      smaskT[w][lane] = word;
    }
  }
  __syncthreads();

  if (tid < 64) {
    u64 mm[13];
#pragma unroll
    for (int w = 0; w < 13; ++w) mm[w] = smaskT[w][lane];
    uint av = 0;
#pragma unroll
    for (int k = 0; k < 4; ++k)
      if (lane + 64 * k < valid) av |= 1u << k;
#define STEP(i) { \
    u64 bm = __ballot((lane == ((i) & 63)) && ((av >> ((i) >> 6)) & 1u)); \
    if (bm) av &= ~((uint)((mm[(i) >> 4] >> (((i) & 15) * 4)) & 0xFULL)); }
#define S4(i)  STEP(i) STEP((i)+1) STEP((i)+2) STEP((i)+3)
#define S16(i) S4(i) S4((i)+4) S4((i)+8) S4((i)+12)
#define S64(i) S16(i) S16((i)+16) S16((i)+32) S16((i)+48)
    S64(0) S64(64) S64(128) S16(192)
#undef S64
#undef S16
#undef S4
#undef STEP
#pragma unroll
    for (int k = 0; k < 4; ++k) {
      u64 bb = __ballot((av >> k) & 1u);
      if (lane == 0) saliveW[k] = bb;
    }
  }
  __syncthreads();

  size_t M = (size_t)C1 * KTOP;
  float* out_boxes  = out;
  float* out_labels = out + (size_t)B * M * 4;
  float* out_scores = out_labels + (size_t)B * M;
  float* out_keep   = out_scores + (size_t)B * M;
  if (tid < KTOP) {
    size_t slot = ((size_t)b * C1 + c) * KTOP + tid;
    bool kept = (tid < valid) && ((saliveW[tid >> 6] >> (tid & 63)) & 1ULL);
    float4 bx = kept ? sbox[tid] : make_float4(0.f, 0.f, 0.f, 0.f);
    reinterpret_cast<float4*>(out_boxes)[slot] = bx;
    out_labels[slot] = kept ? (float)(c + 1) : 0.0f;
    out_scores[slot] = kept ? (float)exp(unflip64(tkeys[(size_t)task * KTOP + tid])) : 0.0f;
    out_keep[slot]   = kept ? 1.0f : 0.0f;
  }
}

extern "C" void kernel_launch(void* const* d_in, const int* in_sizes, int n_in,
                              void* d_out, int out_size, void* d_ws, size_t ws_size,
                              hipStream_t stream) {
  const float* bboxes   = (const float*)d_in[0];
  const float* scores   = (const float*)d_in[1];
  const float* dboxes   = (const float*)d_in[2];
  const float* conf_th  = (const float*)d_in[3];
  const float* nms_th   = (const float*)d_in[4];
  const float* scale_xy = (const float*)d_in[6];
  const float* scale_wh = (const float*)d_in[7];

  int N = in_sizes[2] / 4;
  int B = in_sizes[0] / (4 * N);
  int npad = (N + 7) & ~7;

  // ws: lse | boxes | keys(u16) | ghist | L0cnt | cand(u32) | cnts | tkeys | tbox | tcnt
  char* ws = (char*)d_ws;
  size_t off = 0;
  double* lse     = (double*)(ws + off); off += (size_t)B * N * 8;
  float4* boxesws = (float4*)(ws + off); off += (size_t)B * N * 16;
  u16*    keys    = (u16*)   (ws + off); off += (size_t)B * C1 * npad * 2;
  uint*   ghist   = (uint*)  (ws + off); off += (size_t)B * C1 * 256 * 4;
  uint4*  L0cnt   = (uint4*) (ws + off); off += (size_t)B * C1 * 16;
  uint*   cand    = (uint*)  (ws + off); off += (size_t)B * C1 * SEGS * SEGCAP * 4;
  uint*   cnts    = (uint*)  (ws + off); off += (size_t)B * C1 * SEGS * 4;
  u64*    tkeys   = (u64*)   (ws + off); off += (size_t)B * C1 * KTOP * 8;
  float4* tbox    = (float4*)(ws + off); off += (size_t)B * C1 * KTOP * 16;
  uint*   tcnt    = (uint*)  (ws + off);

  hipMemsetAsync(ghist, 0, (size_t)B * C1 * 256 * 4, stream);

  int perblk = (N + NSPLIT - 1) / NSPLIT;
  prep_kernel<<<B * NSPLIT, NT, 0, stream>>>(
      bboxes, scores, dboxes, conf_th, scale_xy, scale_wh,
      boxesws, lse, keys, ghist, B, N, npad, perblk);

  collect_kernel<<<B * C1 * SEGS, NT, 0, stream>>>(
      keys, ghist, L0cnt, cand, cnts, npad);

  topk_kernel<<<B * C1, NT, 0, stream>>>(
      keys, L0cnt, cand, cnts, scores, lse, boxesws, tkeys, tbox, tcnt, B, N, npad);

  maskresolve_kernel<<<B * C1, NT, 0, stream>>>(
      tkeys, tbox, tcnt, nms_th, (float*)d_out, B);
}

// Round 11
// 94.638 us; speedup vs baseline: 1.9547x; 1.1172x over previous
//
#include <hip/hip_runtime.h>
#include <math.h>

typedef unsigned int uint;
typedef unsigned short u16;
typedef unsigned long long u64;

#define NT 256
#define KTOP 200
#define CAP 256      // final candidate cap == NT (rank-sort)
#define CAPC 3072    // LDS candidate-list cap
#define SEGS 4       // collect segments per task
#define SEGCAP 512   // per-segment candidate cap in global
#define NCLS 21
#define C1 20
#define MROWS 208
#define NSPLIT 48    // prep blocks per batch image

__device__ __forceinline__ u64 flip64(double d) {
  u64 u = (u64)__double_as_longlong(d);
  return (u & 0x8000000000000000ULL) ? ~u : (u | 0x8000000000000000ULL);
}

__device__ __forceinline__ double unflip64(u64 k) {
  u64 u = (k & 0x8000000000000000ULL) ? (k ^ 0x8000000000000000ULL) : ~k;
  return __longlong_as_double((long long)u);
}

// monotone u16 fixed-point key for s = log prob; 0 = invalid
__device__ __forceinline__ uint q_key16(float sf) {
  float qf = (sf + 16.0f) * 4096.0f;
  qf = fmaxf(fminf(qf, 65535.0f), 1.0f);
  return (uint)qf;
}

// parallel 256-bin suffix-scan walk: bin = max j with S[j] >= rank.
__device__ __forceinline__ void par_walk(const uint* hist, uint* scan, u64* wm,
                                         uint* res, uint rank, int tid) {
  scan[tid] = hist[tid];
  __syncthreads();
#pragma unroll
  for (int off = 1; off < 256; off <<= 1) {
    uint v = scan[tid];
    uint a = (tid + off < 256) ? scan[tid + off] : 0u;
    __syncthreads();
    scan[tid] = v + a;
    __syncthreads();
  }
  u64 m = __ballot(scan[tid] >= rank);
  if ((tid & 63) == 0) wm[tid >> 6] = m;
  __syncthreads();
  if (tid == 0) {
    int bin = 0;
    for (int w = 3; w >= 0; --w) {
      if (wm[w]) { bin = w * 64 + (63 - __clzll(wm[w])); break; }
    }
    res[0] = (uint)bin;
    res[1] = scan[bin];
    res[2] = hist[bin];
  }
  __syncthreads();
}

// ---- K1: decode boxes + LSE (hw f32 exp, f64 accum) + u16 keys + hist --------
__global__ __launch_bounds__(NT) void prep_kernel(
    const float* __restrict__ bboxes, const float* __restrict__ scores,
    const float* __restrict__ dboxes, const float* __restrict__ conf_th,
    const float* __restrict__ scale_xy_p, const float* __restrict__ scale_wh_p,
    float4* __restrict__ boxes_out, double* __restrict__ lse_out,
    u16* __restrict__ keys_out, uint* __restrict__ ghist,
    int B, int N, int npad, int perblk)
{
  __shared__ double s_logth[C1];
  __shared__ uint lhist[C1 * 256];
  int tid = threadIdx.x;
  if (tid < C1) s_logth[tid] = log((double)conf_th[tid]);
  for (int i = tid; i < C1 * 256; i += NT) lhist[i] = 0;
  __syncthreads();

  int b = blockIdx.x / NSPLIT, j = blockIdx.x - b * NSPLIT;
  int s0 = j * perblk, e0 = min(N, s0 + perblk);
  float sxy = *scale_xy_p, swh = *scale_wh_p;

  for (int n = s0 + tid; n < e0; n += NT) {
    int gid = b * N + n;
    const float* bb = bboxes + (size_t)b * 4 * N + n;
    float bx = bb[0];
    float by = bb[(size_t)N];
    float bw = bb[2 * (size_t)N];
    float bh = bb[3 * (size_t)N];
    float4 d = reinterpret_cast<const float4*>(dboxes)[n];
    float x = sxy * bx * d.z + d.x;
    float y = sxy * by * d.w + d.y;
    float w = expf(swh * bw) * d.z;
    float h = expf(swh * bh) * d.w;
    boxes_out[gid] = make_float4(x - 0.5f * w, y - 0.5f * h, x + 0.5f * w, y + 0.5f * h);

    const float* sc = scores + (size_t)b * NCLS * N + n;
    float v[NCLS];
    float mx = -INFINITY;
#pragma unroll
    for (int c = 0; c < NCLS; ++c) { v[c] = sc[(size_t)c * N]; mx = fmaxf(mx, v[c]); }
    // hardware f32 exps, three independent f64 accumulators (short dep chains)
    double sum0 = 0.0, sum1 = 0.0, sum2 = 0.0;
#pragma unroll
    for (int c = 0; c < NCLS; ++c) {
      float e = __expf(v[c] - mx);
      if ((c % 3) == 0) sum0 += (double)e;
      else if ((c % 3) == 1) sum1 += (double)e;
      else sum2 += (double)e;
    }
    double lse = (double)mx + log(sum0 + sum1 + sum2);
    lse_out[gid] = lse;

#pragma unroll
    for (int c = 0; c < C1; ++c) {
      double s = (double)v[c + 1] - lse;
      uint key = 0;
      if (s > s_logth[c]) key = q_key16((float)s);
      keys_out[((size_t)b * C1 + c) * npad + n] = (u16)key;
      if (key) atomicAdd(&lhist[c * 256 + (key >> 8)], 1u);
    }
  }
  if (j == NSPLIT - 1 && npad > N) {
    int pad = npad - N;
    for (int t = tid; t < pad * C1; t += NT) {
      int c = t / pad, n = N + (t - c * pad);
      keys_out[((size_t)b * C1 + c) * npad + n] = 0;
    }
  }
  __syncthreads();
  for (int i = tid; i < C1 * 256; i += NT) {
    uint v = lhist[i];
    if (v) atomicAdd(&ghist[((size_t)b * C1 + (i >> 8)) * 256 + (i & 255)], v);
  }
}

// ---- K2: inline walk + distributed collect (B*C1*SEGS blocks, u16 keys) ------
__global__ __launch_bounds__(NT) void collect_kernel(
    const u16* __restrict__ keys, const uint* __restrict__ ghist,
    uint4* __restrict__ L0cnt, uint* __restrict__ cand, uint* __restrict__ cnts,
    int npad)
{
  int blk = blockIdx.x;
  int task = blk >> 2, seg = blk & (SEGS - 1);
  int tid = threadIdx.x, lane = tid & 63;
  __shared__ uint sL, sCnt0, sCnt;

  if (tid < 64) {
    uint4 h = reinterpret_cast<const uint4*>(ghist + (size_t)task * 256)[tid];
    uint s = h.x + h.y + h.z + h.w;
    uint suf = s;
#pragma unroll
    for (int off = 1; off < 64; off <<= 1) {
      uint o = (uint)__shfl_down((int)suf, off);
      if (lane + off < 64) suf += o;
    }
    uint total = (uint)__shfl((int)suf, 0);
    uint sn = (uint)__shfl_down((int)suf, 1);
    if (lane == 63) sn = 0;
    uint c3 = h.w + sn, c2 = c3 + h.z, c1 = c2 + h.y, c0 = c1 + h.x;
    uint binoff, cnt, abv;
    if (c3 >= KTOP)      { binoff = 3; cnt = c3; abv = c3 - h.w; }
    else if (c2 >= KTOP) { binoff = 2; cnt = c2; abv = c2 - h.z; }
    else if (c1 >= KTOP) { binoff = 1; cnt = c1; abv = c1 - h.y; }
    else                 { binoff = 0; cnt = c0; abv = c0 - h.x; }
    uint L0v, cnt0v, abovev;
    if (total < KTOP) {
      L0v = 1u; cnt0v = total; abovev = 0u;
    } else {
      u64 m = __ballot(suf >= KTOP);
      int l = 63 - __clzll(m);
      uint bo = (uint)__shfl((int)binoff, l);
      cnt0v = (uint)__shfl((int)cnt, l);
      abovev = (uint)__shfl((int)abv, l);
      L0v = ((uint)(4 * l) + bo) << 8;
    }
    if (lane == 0) {
      sL = L0v; sCnt0 = cnt0v;
      if (seg == 0) L0cnt[task] = make_uint4(L0v, cnt0v, abovev, total);
    }
  }
  if (tid == NT - 1) sCnt = 0;
  __syncthreads();

  uint L = sL, cnt0 = sCnt0;
  if (cnt0 > CAPC) { if (tid == 0) cnts[blk] = 0; return; }   // slow path in F1

  const u16* krow = keys + (size_t)task * npad;
  const uint4* krow8 = reinterpret_cast<const uint4*>(krow);
  int nv8 = npad >> 3;
  int per8 = (nv8 + SEGS - 1) >> 2;
  int s8 = seg * per8, e8 = min(nv8, s8 + per8);
  uint* myc = cand + ((size_t)task * SEGS + seg) * SEGCAP;

  for (int i = s8 + tid; i < e8; i += NT) {
    uint4 kv = krow8[i];
    uint base = (uint)(i << 3);
    uint ks[8] = { kv.x & 0xFFFFu, kv.x >> 16, kv.y & 0xFFFFu, kv.y >> 16,
                   kv.z & 0xFFFFu, kv.z >> 16, kv.w & 0xFFFFu, kv.w >> 16 };
#pragma unroll
    for (int comp = 0; comp < 8; ++comp) {
      uint k = ks[comp];
      bool f = (k >= L);
      u64 m = __ballot(f);
      if (m) {
        uint nb = (uint)__popcll(m);
        uint wb = 0;
        if (lane == 0) wb = atomicAdd(&sCnt, nb);
        wb = (uint)__shfl((int)wb, 0);
        if (f) {
          uint pos = wb + (uint)__popcll(m & ((1ULL << lane) - 1ULL));
          if (pos < SEGCAP) myc[pos] = (k << 15) | (base + comp);
        }
      }
    }
  }
  __syncthreads();
  if (tid == 0) cnts[blk] = sCnt;      // actual (uncapped) count
}

// ---- F1: narrow -> gather (+box prefetch) -> rank-sort -> write top-K --------
__global__ __launch_bounds__(NT) void topk_kernel(
    const u16* __restrict__ keys, const uint4* __restrict__ L0cnt,
    const uint* __restrict__ candg, const uint* __restrict__ cnts,
    const float* __restrict__ scores, const double* __restrict__ lse,
    const float4* __restrict__ boxesws,
    u64* __restrict__ tkeys, float4* __restrict__ tbox, uint* __restrict__ tcnt,
    int B, int N, int npad)
{
  int task = blockIdx.x;
  int b = task / C1, c = task - b * C1;
  int tid = threadIdx.x, lane = tid & 63;
  const u16* krow = keys + (size_t)task * npad;
  int nv8 = npad >> 3;

  __shared__ uint cand[CAPC];            // 12 KB
  __shared__ uint histB[256];
  __shared__ uint scanB[256];
  __shared__ u64 wmB[4];
  __shared__ uint res3[4];
  __shared__ uint scq[SEGS];
  __shared__ int si[CAP];
  __shared__ u64 sC[CAP];
  __shared__ float4 sbx[CAP];
  __shared__ uint sCnt, sCnt2;

  uint4 w0 = L0cnt[task];
  uint cnt0 = w0.y;
  if (tid < SEGS) scq[tid] = cnts[task * SEGS + tid];
  if (tid == 0) { sCnt = 0; sCnt2 = 0; }
  __syncthreads();
  bool slow = (cnt0 > CAPC) ||
              (scq[0] > SEGCAP) || (scq[1] > SEGCAP) ||
              (scq[2] > SEGCAP) || (scq[3] > SEGCAP);

  uint pref = w0.x >> 8, above = w0.z, rank = KTOP - w0.z;
  uint cnt;

  if (!slow) {
    uint off1 = scq[0], off2 = off1 + scq[1], off3 = off2 + scq[2];
    cnt = off3 + scq[3];
    const uint* cg = candg + (size_t)task * SEGS * SEGCAP;
    for (int j = tid; j < (int)scq[0]; j += NT) cand[j] = cg[j];
    for (int j = tid; j < (int)scq[1]; j += NT) cand[off1 + j] = cg[SEGCAP + j];
    for (int j = tid; j < (int)scq[2]; j += NT) cand[off2 + j] = cg[2 * SEGCAP + j];
    for (int j = tid; j < (int)scq[3]; j += NT) cand[off3 + j] = cg[3 * SEGCAP + j];
    __syncthreads();
  } else {
    const uint4* krow8 = reinterpret_cast<const uint4*>(krow);
    histB[tid] = 0;
    __syncthreads();
    for (int i = tid; i < nv8; i += NT) {
      uint4 kv = krow8[i];
      uint ks[8] = { kv.x & 0xFFFFu, kv.x >> 16, kv.y & 0xFFFFu, kv.y >> 16,
                     kv.z & 0xFFFFu, kv.z >> 16, kv.w & 0xFFFFu, kv.w >> 16 };
#pragma unroll
      for (int comp = 0; comp < 8; ++comp) {
        uint k = ks[comp];
        if ((k >> 8) == pref) atomicAdd(&histB[k & 255u], 1u);
      }
    }
    __syncthreads();
    par_walk(histB, scanB, wmB, res3, rank, tid);
    uint Ts = (pref << 8) | res3[0];
    for (int i = tid; i < nv8; i += NT) {
      uint4 kv = krow8[i];
      uint base = (uint)(i << 3);
      uint ks[8] = { kv.x & 0xFFFFu, kv.x >> 16, kv.y & 0xFFFFu, kv.y >> 16,
                     kv.z & 0xFFFFu, kv.z >> 16, kv.w & 0xFFFFu, kv.w >> 16 };
#pragma unroll
      for (int comp = 0; comp < 8; ++comp) {
        uint k = ks[comp];
        bool f = (k >= Ts);
        u64 m = __ballot(f);
        if (m) {
          uint nb = (uint)__popcll(m);
          uint wb = 0;
          if (lane == 0) wb = atomicAdd(&sCnt, nb);
          wb = (uint)__shfl((int)wb, 0);
          if (f) {
            uint pos = wb + (uint)__popcll(m & ((1ULL << lane) - 1ULL));
            if (pos < CAPC) cand[pos] = (k << 15) | (base + comp);
          }
        }
      }
    }
    __syncthreads();
    cnt = min(sCnt, (uint)CAPC);
  }

  // ---------- narrow candidate list to <= CAP (one 256-bin level, exact key)
  uint cntF;
  if (cnt <= CAP) {
    for (int p = tid; p < (int)cnt; p += NT) si[p] = (int)(cand[p] & 0x7FFFu);
    __syncthreads();
    cntF = cnt;
  } else {
    histB[tid] = 0;
    __syncthreads();
    for (int p = tid; p < (int)cnt; p += NT) {
      uint k = cand[p] >> 15;
      if ((k >> 8) == pref) atomicAdd(&histB[k & 255u], 1u);
    }
    __syncthreads();
    par_walk(histB, scanB, wmB, res3, rank, tid);
    uint T = (pref << 8) | res3[0];
    for (int p = tid; p < (int)cnt; p += NT) {
      uint cd = cand[p];
      if ((cd >> 15) >= T) {
        uint q = atomicAdd(&sCnt2, 1u);
        if (q < CAP) si[q] = (int)(cd & 0x7FFFu);
      }
    }
    __syncthreads();
    cntF = min(sCnt2, (uint)CAP);
  }

  // ---------- gather f64 score + box; composite key, idx tiebreak in low 15
  {
    int p = tid;
    u64 C;
    if (p < (int)cntF) {
      int n = si[p];
      double s = (double)scores[((size_t)b * NCLS + (c + 1)) * N + n] - lse[(size_t)b * N + n];
      u64 f = flip64(s);
      C = (f & ~0x7FFFULL) | (u64)(32767 - n);
      sbx[p] = boxesws[(size_t)b * N + n];
    } else {
      C = (u64)p;
      sbx[p] = make_float4(0.f, 0.f, 0.f, 0.f);
    }
    sC[p] = C;
  }
  __syncthreads();

  // ---------- rank-sort: single u64 compare (keys all distinct)
  {
    u64 kp = sC[tid];
    int r = 0;
#pragma unroll 8
    for (int jj = 0; jj < CAP; ++jj) r += (sC[jj] > kp) ? 1 : 0;
    if (r < KTOP) {
      tkeys[(size_t)task * KTOP + r] = kp;
      tbox[(size_t)task * KTOP + r] = sbx[tid];
    }
  }
  if (tid == 0) tcnt[task] = min(cntF, (uint)KTOP);
}

// ---- F2: register-blocked mask + 1-wave resolve + output --------------------
__global__ __launch_bounds__(NT) void maskresolve_kernel(
    const u64* __restrict__ tkeys, const float4* __restrict__ tbox,
    const uint* __restrict__ tcnt, const float* __restrict__ nms_th_p,
    float* __restrict__ out, int B)
{
  int task = blockIdx.x;
  int b = task / C1, c = task - b * C1;
  int tid = threadIdx.x, lane = tid & 63, wav = tid >> 6;

  __shared__ float4 sbox[MROWS];
  __shared__ float sar[MROWS];
  __shared__ u64 smaskT[13][64];
  __shared__ u64 saliveW[4];

  int valid = (int)tcnt[task];
  float nth = *nms_th_p;

  if (tid < MROWS) {
    float4 bx = (tid < valid) ? tbox[(size_t)task * KTOP + tid]
                              : make_float4(0.f, 0.f, 0.f, 0.f);
    sbox[tid] = bx;
    sar[tid] = fmaxf(bx.z - bx.x, 0.f) * fmaxf(bx.w - bx.y, 0.f);
  }
  __syncthreads();

  {
    float4 jb0 = sbox[lane], jb1 = sbox[lane + 64], jb2 = sbox[lane + 128];
    float4 jb3 = (lane + 192 < MROWS) ? sbox[lane + 192]
                                      : make_float4(0.f, 0.f, 0.f, 0.f);
    float ja0 = sar[lane], ja1 = sar[lane + 64], ja2 = sar[lane + 128],
          ja3 = (lane + 192 < MROWS) ? sar[lane + 192] : 0.f;
    for (int w = wav; w < 13; w += 4) {
      u64 word = 0;
      int r0 = w * 16;
#pragma unroll
      for (int rr = 0; rr < 16; ++rr) {
        int r = r0 + rr;
        float4 rb = sbox[r];
        float ra = sar[r];
        uint nib = 0;
#define IOU_BIT(K, JB, JA) { \
        int j = lane + 64 * (K); \
        float xx1 = fmaxf(rb.x, JB.x), yy1 = fmaxf(rb.y, JB.y); \
        float xx2 = fminf(rb.z, JB.z), yy2 = fminf(rb.w, JB.w); \
        float ww = fmaxf(xx2 - xx1, 0.f), hh = fmaxf(yy2 - yy1, 0.f); \
        float inter = ww * hh; \
        float den = ((ra + JA) - inter) + 1e-9f; \
        if ((inter >= nth * den) && (j > r)) nib |= 1u << (K); }
        IOU_BIT(0, jb0, ja0) IOU_BIT(1, jb1, ja1)
        IOU_BIT(2, jb2, ja2) IOU_BIT(3, jb3, ja3)
#undef IOU_BIT
        word |= (u64)nib << (rr * 4);
      }
      smaskT[w][lane] = word;
    }
  }
  __syncthreads();

  if (tid < 64) {
    u64 mm[13];
#pragma unroll
    for (int w = 0; w < 13; ++w) mm[w] = smaskT[w][lane];
    uint av = 0;
#pragma unroll
    for (int k = 0; k < 4; ++k)
      if (lane + 64 * k < valid) av |= 1u << k;
#define STEP(i) { \
    u64 bm = __ballot((lane == ((i) & 63)) && ((av >> ((i) >> 6)) & 1u)); \
    if (bm) av &= ~((uint)((mm[(i) >> 4] >> (((i) & 15) * 4)) & 0xFULL)); }
#define S4(i)  STEP(i) STEP((i)+1) STEP((i)+2) STEP((i)+3)
#define S16(i) S4(i) S4((i)+4) S4((i)+8) S4((i)+12)
#define S64(i) S16(i) S16((i)+16) S16((i)+32) S16((i)+48)
    S64(0) S64(64) S64(128) S16(192)
#undef S64
#undef S16
#undef S4
#undef STEP
#pragma unroll
    for (int k = 0; k < 4; ++k) {
      u64 bb = __ballot((av >> k) & 1u);
      if (lane == 0) saliveW[k] = bb;
    }
  }
  __syncthreads();

  size_t M = (size_t)C1 * KTOP;
  float* out_boxes  = out;
  float* out_labels = out + (size_t)B * M * 4;
  float* out_scores = out_labels + (size_t)B * M;
  float* out_keep   = out_scores + (size_t)B * M;
  if (tid < KTOP) {
    size_t slot = ((size_t)b * C1 + c) * KTOP + tid;
    bool kept = (tid < valid) && ((saliveW[tid >> 6] >> (tid & 63)) & 1ULL);
    float4 bx = kept ? sbox[tid] : make_float4(0.f, 0.f, 0.f, 0.f);
    reinterpret_cast<float4*>(out_boxes)[slot] = bx;
    out_labels[slot] = kept ? (float)(c + 1) : 0.0f;
    out_scores[slot] = kept ? (float)exp(unflip64(tkeys[(size_t)task * KTOP + tid])) : 0.0f;
    out_keep[slot]   = kept ? 1.0f : 0.0f;
  }
}

extern "C" void kernel_launch(void* const* d_in, const int* in_sizes, int n_in,
                              void* d_out, int out_size, void* d_ws, size_t ws_size,
                              hipStream_t stream) {
  const float* bboxes   = (const float*)d_in[0];
  const float* scores   = (const float*)d_in[1];
  const float* dboxes   = (const float*)d_in[2];
  const float* conf_th  = (const float*)d_in[3];
  const float* nms_th   = (const float*)d_in[4];
  const float* scale_xy = (const float*)d_in[6];
  const float* scale_wh = (const float*)d_in[7];

  int N = in_sizes[2] / 4;
  int B = in_sizes[0] / (4 * N);
  int npad = (N + 7) & ~7;

  // ws: lse | boxes | keys(u16) | ghist | L0cnt | cand(u32) | cnts | tkeys | tbox | tcnt
  char* ws = (char*)d_ws;
  size_t off = 0;
  double* lse     = (double*)(ws + off); off += (size_t)B * N * 8;
  float4* boxesws = (float4*)(ws + off); off += (size_t)B * N * 16;
  u16*    keys    = (u16*)   (ws + off); off += (size_t)B * C1 * npad * 2;
  uint*   ghist   = (uint*)  (ws + off); off += (size_t)B * C1 * 256 * 4;
  uint4*  L0cnt   = (uint4*) (ws + off); off += (size_t)B * C1 * 16;
  uint*   cand    = (uint*)  (ws + off); off += (size_t)B * C1 * SEGS * SEGCAP * 4;
  uint*   cnts    = (uint*)  (ws + off); off += (size_t)B * C1 * SEGS * 4;
  u64*    tkeys   = (u64*)   (ws + off); off += (size_t)B * C1 * KTOP * 8;
  float4* tbox    = (float4*)(ws + off); off += (size_t)B * C1 * KTOP * 16;
  uint*   tcnt    = (uint*)  (ws + off);

  hipMemsetAsync(ghist, 0, (size_t)B * C1 * 256 * 4, stream);

  int perblk = (N + NSPLIT - 1) / NSPLIT;
  prep_kernel<<<B * NSPLIT, NT, 0, stream>>>(
      bboxes, scores, dboxes, conf_th, scale_xy, scale_wh,
      boxesws, lse, keys, ghist, B, N, npad, perblk);

  collect_kernel<<<B * C1 * SEGS, NT, 0, stream>>>(
      keys, ghist, L0cnt, cand, cnts, npad);

  topk_kernel<<<B * C1, NT, 0, stream>>>(
      keys, L0cnt, cand, cnts, scores, lse, boxesws, tkeys, tbox, tcnt, B, N, npad);

  maskresolve_kernel<<<B * C1, NT, 0, stream>>>(
      tkeys, tbox, tcnt, nms_th, (float*)d_out, B);
}